// Round 12
// baseline (436.035 us; speedup 1.0000x reference)
//
#include <hip/hip_runtime.h>
#include <math.h>

// MambaMIL: bf16-MFMA GEMMs + fp32 scan.
// R12: fuse the delta pipeline (dt@W_dt + softplus) INTO scan_phaseA/C:
//   each scan thread computes delta[t][d] from LDS-staged xdbl rows and a
//   register-held W_dt column (32 FMA/t). Removes gemm_f32 (2 dispatches),
//   the 16MB delta buffer, and its 48MB of HBM traffic. Math bit-compatible
//   (same softplus formula, fp32).

#define LSEQ 4096
#define DMODEL 512
#define DINNER 1024
#define DSTATE 16
#define DTRANK 32
#define NCHUNK 256
#define CHLEN 16
#define ATTH 128
#define LOG2E 1.4426950408889634f

enum { ACT_NONE = 0, ACT_RELU = 1, ACT_SOFTPLUS = 2 };

typedef __attribute__((ext_vector_type(8))) short bf16x8;
typedef __attribute__((ext_vector_type(4))) float f32x4;
using gas1 = const __attribute__((address_space(1))) void;
using las3 = __attribute__((address_space(3))) void;

__device__ __forceinline__ float wave_sum(float v) {
#pragma unroll
  for (int off = 32; off > 0; off >>= 1) v += __shfl_xor(v, off, 64);
  return v;
}
__device__ __forceinline__ float wave_max(float v) {
#pragma unroll
  for (int off = 32; off > 0; off >>= 1) v = fmaxf(v, __shfl_xor(v, off, 64));
  return v;
}
__device__ __forceinline__ float siluf(float x) {
  return x * __builtin_amdgcn_rcpf(1.f + exp2f(-LOG2E * x));
}
__device__ __forceinline__ float softplusf(float x) {
  return fmaxf(x, 0.f) + log1pf(expf(-fabsf(x)));
}

__device__ __forceinline__ ushort f2bf(float f) {
  union { float f; unsigned u; } c;
  c.f = f;
  return (ushort)((c.u + 0x7FFFu + ((c.u >> 16) & 1u)) >> 16);
}

// ---------------- prep: input cast + all weight transposes ----------------
__global__ __launch_bounds__(256) void prep_k(
    const float* __restrict__ in_h, ushort* __restrict__ in_bf,
    const float* __restrict__ W_proj, ushort* __restrict__ WprojT,
    const float* __restrict__ W_in, ushort* __restrict__ W_inT,
    const float* __restrict__ W_out, ushort* __restrict__ W_outT) {
  __shared__ float tbuf[32][33];
  const int b = blockIdx.x;
  if (b < 2048) {
    const size_t i = ((size_t)b * 256 + threadIdx.x) * 8;
    const float4 a = *(const float4*)&in_h[i];
    const float4 c = *(const float4*)&in_h[i + 4];
    ushort4 o0, o1;
    o0.x = f2bf(a.x); o0.y = f2bf(a.y); o0.z = f2bf(a.z); o0.w = f2bf(a.w);
    o1.x = f2bf(c.x); o1.y = f2bf(c.y); o1.z = f2bf(c.z); o1.w = f2bf(c.w);
    *(ushort4*)&in_bf[i] = o0;
    *(ushort4*)&in_bf[i + 4] = o1;
    return;
  }
  int t = b - 2048;
  const float* src;
  ushort* dst;
  int K, N;
  if (t < 512) {
    src = W_proj; dst = WprojT; K = 1024; N = 512;
  } else if (t < 512 + 1024) {
    t -= 512; src = W_in; dst = W_inT; K = 512; N = 2048;
  } else if (t < 512 + 2048) {
    t -= 512 + 1024; src = W_in + (size_t)512 * 2048; dst = W_inT + (size_t)2048 * 512;
    K = 512; N = 2048;
  } else if (t < 512 + 2048 + 512) {
    t -= 512 + 2048; src = W_out; dst = W_outT; K = 1024; N = 512;
  } else {
    t -= 512 + 2048 + 512; src = W_out + (size_t)1024 * 512; dst = W_outT + (size_t)512 * 1024;
    K = 1024; N = 512;
  }
  const int tiles_x = N / 32;
  const int n0 = (t % tiles_x) * 32, k0 = (t / tiles_x) * 32;
  const int tx = threadIdx.x & 31, ty = threadIdx.x >> 5;
#pragma unroll
  for (int i = 0; i < 32; i += 8)
    tbuf[ty + i][tx] = src[(size_t)(k0 + ty + i) * N + n0 + tx];
  __syncthreads();
#pragma unroll
  for (int i = 0; i < 32; i += 8)
    dst[(size_t)(n0 + ty + i) * K + k0 + tx] = f2bf(tbuf[tx][ty + i]);
}

// ---------------- bf16 MFMA GEMM: C = act(A @ Bt^T + bias) ----------------
template <int BM, int BN, int ACT, bool BIAS>
__global__ __launch_bounds__(256) void gemm_bf16(
    const ushort* __restrict__ A, const ushort* __restrict__ Bt,
    const float* __restrict__ bias, float* __restrict__ C, int M, int N, int K) {
  constexpr int MI = BM / 32;
  constexpr int NI = BN / 32;
  __shared__ __align__(16) ushort As[BM][32];
  __shared__ __align__(16) ushort Bs[BN][32];
  const int tid = threadIdx.x;
  const int lane = tid & 63;
  const int w = tid >> 6;
  const int wr = (w >> 1) * (BM / 2), wc = (w & 1) * (BN / 2);
  const int fr = lane & 15;
  const int kg = lane >> 4;
  const int bm = blockIdx.y * BM, bn = blockIdx.x * BN;
  const int srow = lane >> 2;
  const int sg = lane & 3;

  f32x4 acc[MI][NI];
#pragma unroll
  for (int i = 0; i < MI; ++i)
#pragma unroll
    for (int j = 0; j < NI; ++j) acc[i][j] = (f32x4){0.f, 0.f, 0.f, 0.f};

  for (int k0 = 0; k0 < K; k0 += 32) {
#pragma unroll
    for (int c = 0; c < BM / 64; ++c) {
      const int row = c * 64 + w * 16 + srow;
      const int g = sg ^ ((row >> 1) & 3);
      __builtin_amdgcn_global_load_lds(
          (gas1*)(A + (size_t)(bm + row) * K + k0 + g * 8),
          (las3*)&As[c * 64 + w * 16][0], 16, 0, 0);
    }
#pragma unroll
    for (int c = 0; c < BN / 64; ++c) {
      const int row = c * 64 + w * 16 + srow;
      const int g = sg ^ ((row >> 1) & 3);
      __builtin_amdgcn_global_load_lds(
          (gas1*)(Bt + (size_t)(bn + row) * K + k0 + g * 8),
          (las3*)&Bs[c * 64 + w * 16][0], 16, 0, 0);
    }
    __syncthreads();
    bf16x8 a[MI], b[NI];
#pragma unroll
    for (int mi = 0; mi < MI; ++mi) {
      const int r = wr + mi * 16 + fr;
      a[mi] = *(const bf16x8*)&As[r][(kg ^ ((r >> 1) & 3)) * 8];
    }
#pragma unroll
    for (int ni = 0; ni < NI; ++ni) {
      const int r = wc + ni * 16 + fr;
      b[ni] = *(const bf16x8*)&Bs[r][(kg ^ ((r >> 1) & 3)) * 8];
    }
#pragma unroll
    for (int mi = 0; mi < MI; ++mi)
#pragma unroll
      for (int ni = 0; ni < NI; ++ni)
        acc[mi][ni] = __builtin_amdgcn_mfma_f32_16x16x32_bf16(
            a[mi], b[ni], acc[mi][ni], 0, 0, 0);
    __syncthreads();
  }

  float bv[NI];
#pragma unroll
  for (int ni = 0; ni < NI; ++ni) bv[ni] = BIAS ? bias[bn + wc + ni * 16 + fr] : 0.f;
#pragma unroll
  for (int mi = 0; mi < MI; ++mi) {
#pragma unroll
    for (int i = 0; i < 4; ++i) {
      const int row = bm + wr + mi * 16 + kg * 4 + i;
      float* crow = &C[(size_t)row * N + bn + wc];
#pragma unroll
      for (int ni = 0; ni < NI; ++ni) {
        float v = acc[mi][ni][i] + bv[ni];
        if (ACT == ACT_RELU) v = fmaxf(v, 0.f);
        crow[ni * 16 + fr] = v;
      }
    }
  }
}

// ---------------- depthwise causal conv (D_CONV=4) + bias + silu ----------
__global__ __launch_bounds__(256) void conv_silu_k(
    const float* __restrict__ xz, const float* __restrict__ Wc,
    const float* __restrict__ bc, float* __restrict__ xc) {
  const int idx = blockIdx.x * 256 + threadIdx.x;
  const int d = idx & (DINNER - 1);
  const int t = idx >> 10;
  const float4 w = *(const float4*)&Wc[d * 4];
  float acc = bc[d];
  if (t >= 3) acc = fmaf(w.x, xz[(size_t)(t - 3) * 2 * DINNER + d], acc);
  if (t >= 2) acc = fmaf(w.y, xz[(size_t)(t - 2) * 2 * DINNER + d], acc);
  if (t >= 1) acc = fmaf(w.z, xz[(size_t)(t - 1) * 2 * DINNER + d], acc);
  acc = fmaf(w.w, xz[(size_t)t * 2 * DINNER + d], acc);
  xc[idx] = siluf(acc);
}

// ---------------- skinny GEMM for W_x: 4096x1024 @ 1024x64 ----------------
__global__ __launch_bounds__(256) void gemm_skinny64(
    const float* __restrict__ A, const float* __restrict__ B, float* __restrict__ C) {
  __shared__ float As[8][DINNER];  // 32 KB
  const int tid = threadIdx.x;
  const int w = tid >> 6;
  const int lane = tid & 63;
  const int j4 = lane & 15;
  const int kk = lane >> 4;
  const int row0 = blockIdx.x * 8;
  for (int i = tid; i < 8 * (DINNER / 4); i += 256) {
    const int r = i >> 8, c = i & 255;
    *(float4*)&As[r][c * 4] = *(const float4*)&A[(size_t)(row0 + r) * DINNER + c * 4];
  }
  __syncthreads();
  const int r0 = w * 2;
  float4 acc0 = {0.f, 0.f, 0.f, 0.f}, acc1 = {0.f, 0.f, 0.f, 0.f};
#pragma unroll 4
  for (int k0 = 0; k0 < DINNER; k0 += 4) {
    const float4 b4 = *(const float4*)&B[(size_t)(k0 + kk) * 64 + j4 * 4];
    const float a0 = As[r0][k0 + kk];
    const float a1 = As[r0 + 1][k0 + kk];
    acc0.x = fmaf(a0, b4.x, acc0.x);
    acc0.y = fmaf(a0, b4.y, acc0.y);
    acc0.z = fmaf(a0, b4.z, acc0.z);
    acc0.w = fmaf(a0, b4.w, acc0.w);
    acc1.x = fmaf(a1, b4.x, acc1.x);
    acc1.y = fmaf(a1, b4.y, acc1.y);
    acc1.z = fmaf(a1, b4.z, acc1.z);
    acc1.w = fmaf(a1, b4.w, acc1.w);
  }
#pragma unroll
  for (int off = 16; off <= 32; off <<= 1) {
    acc0.x += __shfl_xor(acc0.x, off, 64);
    acc0.y += __shfl_xor(acc0.y, off, 64);
    acc0.z += __shfl_xor(acc0.z, off, 64);
    acc0.w += __shfl_xor(acc0.w, off, 64);
    acc1.x += __shfl_xor(acc1.x, off, 64);
    acc1.y += __shfl_xor(acc1.y, off, 64);
    acc1.z += __shfl_xor(acc1.z, off, 64);
    acc1.w += __shfl_xor(acc1.w, off, 64);
  }
  if (kk == 0) {
    *(float4*)&C[(size_t)(row0 + r0) * 64 + j4 * 4] = acc0;
    *(float4*)&C[(size_t)(row0 + r0 + 1) * 64 + j4 * 4] = acc1;
  }
}

// ---------------- LayerNorm (512 cols); optional residual; fp32/bf16 out --
template <bool BF16OUT>
__global__ __launch_bounds__(256) void layernorm_k(
    const float* __restrict__ x, const float* __restrict__ res,
    const float* __restrict__ w, const float* __restrict__ b, void* __restrict__ outp) {
  const int wave = threadIdx.x >> 6, lane = threadIdx.x & 63;
  const int row = blockIdx.x * 4 + wave;
  const size_t base = (size_t)row * DMODEL;
  float4 v0 = *(const float4*)&x[base + lane * 4];
  float4 v1 = *(const float4*)&x[base + 256 + lane * 4];
  if (res != nullptr) {
    const float4 r0 = *(const float4*)&res[base + lane * 4];
    const float4 r1 = *(const float4*)&res[base + 256 + lane * 4];
    v0.x += r0.x; v0.y += r0.y; v0.z += r0.z; v0.w += r0.w;
    v1.x += r1.x; v1.y += r1.y; v1.z += r1.z; v1.w += r1.w;
  }
  float s = (v0.x + v0.y) + (v0.z + v0.w) + (v1.x + v1.y) + (v1.z + v1.w);
  const float mean = wave_sum(s) * (1.f / DMODEL);
  const float d0 = v0.x - mean, d1 = v0.y - mean, d2 = v0.z - mean, d3 = v0.w - mean;
  const float d4 = v1.x - mean, d5 = v1.y - mean, d6 = v1.z - mean, d7 = v1.w - mean;
  float q = (d0 * d0 + d1 * d1) + (d2 * d2 + d3 * d3) + (d4 * d4 + d5 * d5) + (d6 * d6 + d7 * d7);
  const float rstd = rsqrtf(wave_sum(q) * (1.f / DMODEL) + 1e-5f);
  const float4 w0 = *(const float4*)&w[lane * 4];
  const float4 w1 = *(const float4*)&w[256 + lane * 4];
  const float4 b0 = *(const float4*)&b[lane * 4];
  const float4 b1 = *(const float4*)&b[256 + lane * 4];
  float o0 = fmaf(d0 * rstd, w0.x, b0.x), o1 = fmaf(d1 * rstd, w0.y, b0.y);
  float o2 = fmaf(d2 * rstd, w0.z, b0.z), o3 = fmaf(d3 * rstd, w0.w, b0.w);
  float o4 = fmaf(d4 * rstd, w1.x, b1.x), o5 = fmaf(d5 * rstd, w1.y, b1.y);
  float o6 = fmaf(d6 * rstd, w1.z, b1.z), o7 = fmaf(d7 * rstd, w1.w, b1.w);
  if (BF16OUT) {
    ushort* out = (ushort*)outp;
    ushort4 u0, u1;
    u0.x = f2bf(o0); u0.y = f2bf(o1); u0.z = f2bf(o2); u0.w = f2bf(o3);
    u1.x = f2bf(o4); u1.y = f2bf(o5); u1.z = f2bf(o6); u1.w = f2bf(o7);
    *(ushort4*)&out[base + lane * 4] = u0;
    *(ushort4*)&out[base + 256 + lane * 4] = u1;
  } else {
    float* out = (float*)outp;
    float4 f0, f1;
    f0.x = o0; f0.y = o1; f0.z = o2; f0.w = o3;
    f1.x = o4; f1.y = o5; f1.z = o6; f1.w = o7;
    *(float4*)&out[base + lane * 4] = f0;
    *(float4*)&out[base + 256 + lane * 4] = f1;
  }
}

// ---------------- selective scan (delta fused): 3-phase chunked -----------
// delta[t][d] = softplus(xdbl[t][0:32] . W_dt[:,d] + b_dt[d]) computed
// in-register from LDS-staged xdbl rows + register-held W_dt column.
__global__ __launch_bounds__(256) void scan_phaseA(
    const float* __restrict__ xdbl, const float* __restrict__ xc,
    const float* __restrict__ A_log, const float* __restrict__ W_dt,
    const float* __restrict__ b_dt, float* __restrict__ chA,
    float* __restrict__ chB) {
  const int chunk = blockIdx.x >> 2;
  const int d = ((blockIdx.x & 3) << 8) + threadIdx.x;
  __shared__ float Xsh[CHLEN][64];  // full xdbl rows: dt | B | C
  {
    const int t = threadIdx.x >> 4, c4 = threadIdx.x & 15;
    *(float4*)&Xsh[t][c4 * 4] =
        *(const float4*)&xdbl[(size_t)(chunk * CHLEN + t) * 64 + c4 * 4];
  }
  __syncthreads();
  float wdt[DTRANK];
#pragma unroll
  for (int k = 0; k < DTRANK; k += 8) {
#pragma unroll
    for (int u = 0; u < 8; ++u)
      wdt[k + u] = W_dt[(size_t)(k + u) * DINNER + d];
  }
  const float bdt = b_dt[d];
  float Avl2[DSTATE];
#pragma unroll
  for (int s = 0; s < DSTATE; ++s)
    Avl2[s] = -expf(A_log[d * DSTATE + s]) * LOG2E;
  float aP[DSTATE], bP[DSTATE];
#pragma unroll
  for (int s = 0; s < DSTATE; ++s) { aP[s] = 1.f; bP[s] = 0.f; }
  const size_t col = (size_t)chunk * CHLEN * DINNER + d;
  for (int t0 = 0; t0 < CHLEN; t0 += 4) {
    float xv[4];
#pragma unroll
    for (int u = 0; u < 4; ++u)
      xv[u] = xc[col + (size_t)(t0 + u) * DINNER];
    float dl[4];
#pragma unroll
    for (int u = 0; u < 4; ++u) {
      float acc = bdt;
#pragma unroll
      for (int k = 0; k < DTRANK; ++k)
        acc = fmaf(Xsh[t0 + u][k], wdt[k], acc);
      dl[u] = softplusf(acc);
    }
#pragma unroll
    for (int u = 0; u < 4; ++u) {
      const float du = dl[u] * xv[u];
#pragma unroll
      for (int s = 0; s < DSTATE; ++s) {
        const float a = exp2f(dl[u] * Avl2[s]);
        bP[s] = fmaf(a, bP[s], du * Xsh[t0 + u][32 + s]);
        aP[s] *= a;
      }
    }
  }
  const size_t base = (size_t)chunk * DINNER * DSTATE + (size_t)d * DSTATE;
#pragma unroll
  for (int s = 0; s < DSTATE; ++s) {
    chA[base + s] = aP[s];
    chB[base + s] = bP[s];
  }
}

// s0 may alias chB (in-place). 8-deep load batching hides memory latency.
__global__ __launch_bounds__(64) void scan_phaseB(
    const float* chA, const float* chB, float* s0) {
  const int i = blockIdx.x * 64 + threadIdx.x;
  float st = 0.f;
  for (int c0 = 0; c0 < NCHUNK; c0 += 8) {
    float a[8], b[8];
#pragma unroll
    for (int u = 0; u < 8; ++u) {
      const size_t idx = (size_t)(c0 + u) * (DINNER * DSTATE) + i;
      a[u] = chA[idx];
      b[u] = chB[idx];
    }
#pragma unroll
    for (int u = 0; u < 8; ++u) {
      const size_t idx = (size_t)(c0 + u) * (DINNER * DSTATE) + i;
      s0[idx] = st;
      st = fmaf(a[u], st, b[u]);
    }
  }
}

__global__ __launch_bounds__(256) void scan_phaseC(
    const float* __restrict__ xdbl, const float* __restrict__ xc,
    const float* __restrict__ A_log, const float* __restrict__ W_dt,
    const float* __restrict__ b_dt, const float* __restrict__ Dsk,
    const float* __restrict__ s0, const float* __restrict__ xz,
    ushort* __restrict__ y) {
  const int chunk = blockIdx.x >> 2;
  const int d = ((blockIdx.x & 3) << 8) + threadIdx.x;
  __shared__ float Xsh[CHLEN][64];  // dt | B | C
  {
    const int t = threadIdx.x >> 4, c4 = threadIdx.x & 15;
    *(float4*)&Xsh[t][c4 * 4] =
        *(const float4*)&xdbl[(size_t)(chunk * CHLEN + t) * 64 + c4 * 4];
  }
  __syncthreads();
  float wdt[DTRANK];
#pragma unroll
  for (int k = 0; k < DTRANK; k += 8) {
#pragma unroll
    for (int u = 0; u < 8; ++u)
      wdt[k + u] = W_dt[(size_t)(k + u) * DINNER + d];
  }
  const float bdt = b_dt[d];
  float Avl2[DSTATE];
#pragma unroll
  for (int s = 0; s < DSTATE; ++s)
    Avl2[s] = -expf(A_log[d * DSTATE + s]) * LOG2E;
  float st[DSTATE];
  const size_t base = (size_t)chunk * DINNER * DSTATE + (size_t)d * DSTATE;
#pragma unroll
  for (int s = 0; s < DSTATE; ++s) st[s] = s0[base + s];
  const float Dv = Dsk[d];
  const size_t col = (size_t)chunk * CHLEN * DINNER + d;
  const size_t zcol = (size_t)chunk * CHLEN * 2 * DINNER + DINNER + d;
  for (int t0 = 0; t0 < CHLEN; t0 += 4) {
    float xv[4], zv[4];
#pragma unroll
    for (int u = 0; u < 4; ++u) {
      xv[u] = xc[col + (size_t)(t0 + u) * DINNER];
      zv[u] = xz[zcol + (size_t)(t0 + u) * 2 * DINNER];
    }
    float dl[4];
#pragma unroll
    for (int u = 0; u < 4; ++u) {
      float acc = bdt;
#pragma unroll
      for (int k = 0; k < DTRANK; ++k)
        acc = fmaf(Xsh[t0 + u][k], wdt[k], acc);
      dl[u] = softplusf(acc);
    }
    ushort yo[4];
#pragma unroll
    for (int u = 0; u < 4; ++u) {
      const float du = dl[u] * xv[u];
      float yv = 0.f;
#pragma unroll
      for (int s = 0; s < DSTATE; ++s) {
        const float a = exp2f(dl[u] * Avl2[s]);
        st[s] = fmaf(a, st[s], du * Xsh[t0 + u][32 + s]);
        yv = fmaf(st[s], Xsh[t0 + u][48 + s], yv);
      }
      yo[u] = f2bf((yv + xv[u] * Dv) * siluf(zv[u]));
    }
#pragma unroll
    for (int u = 0; u < 4; ++u)
      y[col + (size_t)(t0 + u) * DINNER] = yo[u];
  }
}

// ---------------- attention scores: tanh(h@Wa1+ba1)@Wa2+ba2 ---------------
__global__ __launch_bounds__(256) void attn_scores_k(
    const float* __restrict__ h, const float* __restrict__ Wa1,
    const float* __restrict__ ba1, const float* __restrict__ Wa2,
    const float* __restrict__ ba2, float* __restrict__ scores) {
  __shared__ float hs[8][DMODEL];
  __shared__ float part[8][2][ATTH];
  __shared__ float red[8][2];
  const int tid = threadIdx.x;
  const int j = tid & 127;
  const int half = tid >> 7;
  const int t0 = blockIdx.x * 8;
  for (int i = tid; i < 8 * DMODEL / 4; i += 256) {
    const int rr = i >> 7, cc = i & 127;
    *(float4*)&hs[rr][cc * 4] = *(const float4*)&h[(size_t)(t0 + rr) * DMODEL + cc * 4];
  }
  __syncthreads();
  float acc[8];
#pragma unroll
  for (int rr = 0; rr < 8; ++rr) acc[rr] = 0.f;
  const int kbase = half * 256;
  for (int k0 = 0; k0 < 256; k0 += 4) {
    float wv[4];
#pragma unroll
    for (int u = 0; u < 4; ++u)
      wv[u] = Wa1[(size_t)(kbase + k0 + u) * ATTH + j];
#pragma unroll
    for (int rr = 0; rr < 8; ++rr) {
      const float4 hv = *(const float4*)&hs[rr][kbase + k0];
      acc[rr] = fmaf(hv.x, wv[0], acc[rr]);
      acc[rr] = fmaf(hv.y, wv[1], acc[rr]);
      acc[rr] = fmaf(hv.z, wv[2], acc[rr]);
      acc[rr] = fmaf(hv.w, wv[3], acc[rr]);
    }
  }
#pragma unroll
  for (int rr = 0; rr < 8; ++rr) part[rr][half][j] = acc[rr];
  __syncthreads();
  if (half == 0) {
    const float w2 = Wa2[j];
    const float b1 = ba1[j];
    const int wv_ = j >> 6;
#pragma unroll
    for (int rr = 0; rr < 8; ++rr) {
      float v = tanhf(part[rr][0][j] + part[rr][1][j] + b1) * w2;
      v = wave_sum(v);
      if ((j & 63) == 0) red[rr][wv_] = v;
    }
  }
  __syncthreads();
  if (tid < 8) scores[t0 + tid] = red[tid][0] + red[tid][1] + ba2[0];
}

__global__ __launch_bounds__(1024) void softmax_k(
    const float* __restrict__ s, float* __restrict__ aw) {
  const int tid = threadIdx.x;
  const int wave = tid >> 6, lane = tid & 63;
  const float4 v = *(const float4*)&s[tid * 4];
  float m = fmaxf(fmaxf(v.x, v.y), fmaxf(v.z, v.w));
  m = wave_max(m);
  __shared__ float redm[16];
  if (lane == 0) redm[wave] = m;
  __syncthreads();
  float bm = redm[0];
#pragma unroll
  for (int i = 1; i < 16; ++i) bm = fmaxf(bm, redm[i]);
  const float e0 = expf(v.x - bm), e1 = expf(v.y - bm);
  const float e2 = expf(v.z - bm), e3 = expf(v.w - bm);
  float sum = wave_sum((e0 + e1) + (e2 + e3));
  __shared__ float reds[16];
  if (lane == 0) reds[wave] = sum;
  __syncthreads();
  float Z = 0.f;
#pragma unroll
  for (int i = 0; i < 16; ++i) Z += reds[i];
  const float inv = 1.f / Z;
  float4 o;
  o.x = e0 * inv; o.y = e1 * inv; o.z = e2 * inv; o.w = e3 * inv;
  *(float4*)&aw[tid * 4] = o;
}

__global__ __launch_bounds__(256) void pool_partial_k(
    const float* __restrict__ aw, const float* __restrict__ h, float* __restrict__ part) {
  const int b = blockIdx.x;
  const int tid = threadIdx.x;
  float2 acc = make_float2(0.f, 0.f);
  for (int t = b * 64; t < b * 64 + 64; ++t) {
    const float w = aw[t];
    const float2 hv = *(const float2*)&h[(size_t)t * DMODEL + tid * 2];
    acc.x = fmaf(w, hv.x, acc.x);
    acc.y = fmaf(w, hv.y, acc.y);
  }
  *(float2*)&part[b * DMODEL + tid * 2] = acc;
}

__global__ __launch_bounds__(512) void pool_final_k(
    const float* __restrict__ part, const float* __restrict__ Wh,
    const float* __restrict__ bh, float* __restrict__ out) {
  const int d = threadIdx.x;
  float s = 0.f;
  for (int b = 0; b < 64; ++b) s += part[b * DMODEL + d];
  float v0 = wave_sum(s * Wh[d * 2 + 0]);
  float v1 = wave_sum(s * Wh[d * 2 + 1]);
  __shared__ float r0[8], r1[8];
  const int wave = d >> 6, lane = d & 63;
  if (lane == 0) { r0[wave] = v0; r1[wave] = v1; }
  __syncthreads();
  if (d == 0) {
    float o0 = bh[0], o1 = bh[1];
#pragma unroll
    for (int i = 0; i < 8; ++i) { o0 += r0[i]; o1 += r1[i]; }
    out[0] = o0;
    out[1] = o1;
  }
}

extern "C" void kernel_launch(void* const* d_in, const int* in_sizes, int n_in,
                              void* d_out, int out_size, void* d_ws, size_t ws_size,
                              hipStream_t stream) {
  const float* in_h = (const float*)d_in[0];
  const float* W_proj = (const float*)d_in[1];
  const float* b_proj = (const float*)d_in[2];
  const float* ln_w = (const float*)d_in[3];
  const float* ln_b = (const float*)d_in[4];
  const float* W_in = (const float*)d_in[5];
  const float* W_conv = (const float*)d_in[6];
  const float* b_conv = (const float*)d_in[7];
  const float* W_x = (const float*)d_in[8];
  const float* W_dt = (const float*)d_in[9];
  const float* b_dt = (const float*)d_in[10];
  const float* A_log = (const float*)d_in[11];
  const float* Dsk = (const float*)d_in[12];
  const float* W_out = (const float*)d_in[13];
  const float* norm_w = (const float*)d_in[14];
  const float* norm_b = (const float*)d_in[15];
  const float* Wa1 = (const float*)d_in[16];
  const float* ba1 = (const float*)d_in[17];
  const float* Wa2 = (const float*)d_in[18];
  const float* ba2 = (const float*)d_in[19];
  const float* Wh = (const float*)d_in[20];
  const float* bh = (const float*)d_in[21];
  float* out = (float*)d_out;

  float* ws = (float*)d_ws;
  size_t off = 0;
  auto alloc = [&](size_t n) {
    float* p = ws + off;
    off += (n + 63) & ~(size_t)63;
    return p;
  };
  float* res = alloc((size_t)LSEQ * DMODEL);
  float* hbuf = alloc((size_t)LSEQ * DMODEL);
  float* xz = alloc((size_t)LSEQ * 2 * DINNER);
  float* xc = alloc((size_t)LSEQ * DINNER);
  float* xdbl = alloc((size_t)LSEQ * 64);
  float* chA = alloc((size_t)DINNER * DSTATE * NCHUNK);
  float* chB = alloc((size_t)DINNER * DSTATE * NCHUNK);
  ushort* lnb_bf = (ushort*)alloc((size_t)LSEQ * DMODEL / 2);
  ushort* y_bf = (ushort*)alloc((size_t)LSEQ * DINNER / 2);
  ushort* in_bf = (ushort*)alloc((size_t)LSEQ * 1024 / 2);
  ushort* WprojT = (ushort*)alloc((size_t)DMODEL * 1024 / 2);
  ushort* W_inT = (ushort*)alloc((size_t)2 * 2048 * 512 / 2);
  ushort* W_outT = (ushort*)alloc((size_t)2 * 512 * 1024 / 2);
  (void)ws_size;
  float* s0b = chB;  // phaseB writes prefix-state in-place over chB
  float* hfin = xz;
  float* scores = xz + (size_t)LSEQ * DMODEL;
  float* aw = scores + LSEQ;
  float* part = aw + LSEQ;

  // 0. one-shot prep: input cast + all 5 weight transposes
  prep_k<<<5632, 256, 0, stream>>>(in_h, in_bf, W_proj, WprojT, W_in, W_inT,
                                   W_out, W_outT);
  // 1. proj GEMM (relu+bias) -> res
  gemm_bf16<64, 128, ACT_RELU, true>
      <<<dim3(DMODEL / 128, LSEQ / 64), 256, 0, stream>>>(
          in_bf, WprojT, b_proj, res, LSEQ, DMODEL, 1024);

  const float* cur = res;
  for (int l = 0; l < 2; ++l) {
    layernorm_k<true><<<LSEQ / 4, 256, 0, stream>>>(
        cur, nullptr, ln_w + l * DMODEL, ln_b + l * DMODEL, lnb_bf);
    gemm_bf16<128, 128, ACT_NONE, false>
        <<<dim3(2 * DINNER / 128, LSEQ / 128), 256, 0, stream>>>(
            lnb_bf, W_inT + (size_t)l * 2048 * 512, nullptr, xz, LSEQ,
            2 * DINNER, DMODEL);
    conv_silu_k<<<LSEQ * DINNER / 256, 256, 0, stream>>>(
        xz, W_conv + l * DINNER * 4, b_conv + l * DINNER, xc);
    gemm_skinny64<<<LSEQ / 8, 256, 0, stream>>>(
        xc, W_x + (size_t)l * DINNER * 64, xdbl);
    const float* Al = A_log + (size_t)l * DINNER * DSTATE;
    const float* Wdt_l = W_dt + (size_t)l * DTRANK * DINNER;
    const float* bdt_l = b_dt + (size_t)l * DINNER;
    scan_phaseA<<<NCHUNK * 4, 256, 0, stream>>>(xdbl, xc, Al, Wdt_l, bdt_l,
                                                chA, chB);
    scan_phaseB<<<DINNER * DSTATE / 64, 64, 0, stream>>>(chA, chB, s0b);
    scan_phaseC<<<NCHUNK * 4, 256, 0, stream>>>(
        xdbl, xc, Al, Wdt_l, bdt_l, Dsk + l * DINNER, s0b, xz, y_bf);
    gemm_bf16<64, 128, ACT_NONE, false>
        <<<dim3(DMODEL / 128, LSEQ / 64), 256, 0, stream>>>(
            y_bf, W_outT + (size_t)l * 512 * 1024, nullptr, hbuf, LSEQ, DMODEL,
            DINNER);
    cur = hbuf;
  }

  layernorm_k<false><<<LSEQ / 4, 256, 0, stream>>>(cur, res, norm_w, norm_b, hfin);
  attn_scores_k<<<LSEQ / 8, 256, 0, stream>>>(hfin, Wa1, ba1, Wa2, ba2, scores);
  softmax_k<<<1, 1024, 0, stream>>>(scores, aw);
  pool_partial_k<<<64, 256, 0, stream>>>(aw, hfin, part);
  pool_final_k<<<1, 512, 0, stream>>>(part, Wh, bh, out);
}

// Round 13
// 426.867 us; speedup vs baseline: 1.0215x; 1.0215x over previous
//
#include <hip/hip_runtime.h>
#include <math.h>

// MambaMIL: bf16-MFMA GEMMs + fp32 scan.
// R13: REVERT R12's delta fusion (regression: phaseA 30->50us; dt dot-product
//      computed twice with no data reuse, +60% VALU on a VALU-bound kernel).
//      Restored R11 structure: prep_k + gload_lds GEMMs + separate gemm_f32
//      for delta + 3-phase scan. Best known: 426us.

#define LSEQ 4096
#define DMODEL 512
#define DINNER 1024
#define DSTATE 16
#define DTRANK 32
#define NCHUNK 256
#define CHLEN 16
#define ATTH 128
#define LOG2E 1.4426950408889634f

enum { ACT_NONE = 0, ACT_RELU = 1, ACT_SOFTPLUS = 2 };

typedef __attribute__((ext_vector_type(8))) short bf16x8;
typedef __attribute__((ext_vector_type(4))) float f32x4;
using gas1 = const __attribute__((address_space(1))) void;
using las3 = __attribute__((address_space(3))) void;

__device__ __forceinline__ float wave_sum(float v) {
#pragma unroll
  for (int off = 32; off > 0; off >>= 1) v += __shfl_xor(v, off, 64);
  return v;
}
__device__ __forceinline__ float wave_max(float v) {
#pragma unroll
  for (int off = 32; off > 0; off >>= 1) v = fmaxf(v, __shfl_xor(v, off, 64));
  return v;
}
__device__ __forceinline__ float siluf(float x) {
  return x * __builtin_amdgcn_rcpf(1.f + exp2f(-LOG2E * x));
}

__device__ __forceinline__ ushort f2bf(float f) {
  union { float f; unsigned u; } c;
  c.f = f;
  return (ushort)((c.u + 0x7FFFu + ((c.u >> 16) & 1u)) >> 16);
}

// ---------------- prep: input cast + all weight transposes ----------------
__global__ __launch_bounds__(256) void prep_k(
    const float* __restrict__ in_h, ushort* __restrict__ in_bf,
    const float* __restrict__ W_proj, ushort* __restrict__ WprojT,
    const float* __restrict__ W_in, ushort* __restrict__ W_inT,
    const float* __restrict__ W_out, ushort* __restrict__ W_outT) {
  __shared__ float tbuf[32][33];
  const int b = blockIdx.x;
  if (b < 2048) {
    const size_t i = ((size_t)b * 256 + threadIdx.x) * 8;
    const float4 a = *(const float4*)&in_h[i];
    const float4 c = *(const float4*)&in_h[i + 4];
    ushort4 o0, o1;
    o0.x = f2bf(a.x); o0.y = f2bf(a.y); o0.z = f2bf(a.z); o0.w = f2bf(a.w);
    o1.x = f2bf(c.x); o1.y = f2bf(c.y); o1.z = f2bf(c.z); o1.w = f2bf(c.w);
    *(ushort4*)&in_bf[i] = o0;
    *(ushort4*)&in_bf[i + 4] = o1;
    return;
  }
  int t = b - 2048;
  const float* src;
  ushort* dst;
  int K, N;
  if (t < 512) {
    src = W_proj; dst = WprojT; K = 1024; N = 512;
  } else if (t < 512 + 1024) {
    t -= 512; src = W_in; dst = W_inT; K = 512; N = 2048;
  } else if (t < 512 + 2048) {
    t -= 512 + 1024; src = W_in + (size_t)512 * 2048; dst = W_inT + (size_t)2048 * 512;
    K = 512; N = 2048;
  } else if (t < 512 + 2048 + 512) {
    t -= 512 + 2048; src = W_out; dst = W_outT; K = 1024; N = 512;
  } else {
    t -= 512 + 2048 + 512; src = W_out + (size_t)1024 * 512; dst = W_outT + (size_t)512 * 1024;
    K = 1024; N = 512;
  }
  const int tiles_x = N / 32;
  const int n0 = (t % tiles_x) * 32, k0 = (t / tiles_x) * 32;
  const int tx = threadIdx.x & 31, ty = threadIdx.x >> 5;
#pragma unroll
  for (int i = 0; i < 32; i += 8)
    tbuf[ty + i][tx] = src[(size_t)(k0 + ty + i) * N + n0 + tx];
  __syncthreads();
#pragma unroll
  for (int i = 0; i < 32; i += 8)
    dst[(size_t)(n0 + ty + i) * K + k0 + tx] = f2bf(tbuf[tx][ty + i]);
}

// ---------------- bf16 MFMA GEMM: C = act(A @ Bt^T + bias) ----------------
template <int BM, int BN, int ACT, bool BIAS>
__global__ __launch_bounds__(256) void gemm_bf16(
    const ushort* __restrict__ A, const ushort* __restrict__ Bt,
    const float* __restrict__ bias, float* __restrict__ C, int M, int N, int K) {
  constexpr int MI = BM / 32;
  constexpr int NI = BN / 32;
  __shared__ __align__(16) ushort As[BM][32];
  __shared__ __align__(16) ushort Bs[BN][32];
  const int tid = threadIdx.x;
  const int lane = tid & 63;
  const int w = tid >> 6;
  const int wr = (w >> 1) * (BM / 2), wc = (w & 1) * (BN / 2);
  const int fr = lane & 15;
  const int kg = lane >> 4;
  const int bm = blockIdx.y * BM, bn = blockIdx.x * BN;
  const int srow = lane >> 2;
  const int sg = lane & 3;

  f32x4 acc[MI][NI];
#pragma unroll
  for (int i = 0; i < MI; ++i)
#pragma unroll
    for (int j = 0; j < NI; ++j) acc[i][j] = (f32x4){0.f, 0.f, 0.f, 0.f};

  for (int k0 = 0; k0 < K; k0 += 32) {
#pragma unroll
    for (int c = 0; c < BM / 64; ++c) {
      const int row = c * 64 + w * 16 + srow;
      const int g = sg ^ ((row >> 1) & 3);
      __builtin_amdgcn_global_load_lds(
          (gas1*)(A + (size_t)(bm + row) * K + k0 + g * 8),
          (las3*)&As[c * 64 + w * 16][0], 16, 0, 0);
    }
#pragma unroll
    for (int c = 0; c < BN / 64; ++c) {
      const int row = c * 64 + w * 16 + srow;
      const int g = sg ^ ((row >> 1) & 3);
      __builtin_amdgcn_global_load_lds(
          (gas1*)(Bt + (size_t)(bn + row) * K + k0 + g * 8),
          (las3*)&Bs[c * 64 + w * 16][0], 16, 0, 0);
    }
    __syncthreads();
    bf16x8 a[MI], b[NI];
#pragma unroll
    for (int mi = 0; mi < MI; ++mi) {
      const int r = wr + mi * 16 + fr;
      a[mi] = *(const bf16x8*)&As[r][(kg ^ ((r >> 1) & 3)) * 8];
    }
#pragma unroll
    for (int ni = 0; ni < NI; ++ni) {
      const int r = wc + ni * 16 + fr;
      b[ni] = *(const bf16x8*)&Bs[r][(kg ^ ((r >> 1) & 3)) * 8];
    }
#pragma unroll
    for (int mi = 0; mi < MI; ++mi)
#pragma unroll
      for (int ni = 0; ni < NI; ++ni)
        acc[mi][ni] = __builtin_amdgcn_mfma_f32_16x16x32_bf16(
            a[mi], b[ni], acc[mi][ni], 0, 0, 0);
    __syncthreads();
  }

  float bv[NI];
#pragma unroll
  for (int ni = 0; ni < NI; ++ni) bv[ni] = BIAS ? bias[bn + wc + ni * 16 + fr] : 0.f;
#pragma unroll
  for (int mi = 0; mi < MI; ++mi) {
#pragma unroll
    for (int i = 0; i < 4; ++i) {
      const int row = bm + wr + mi * 16 + kg * 4 + i;
      float* crow = &C[(size_t)row * N + bn + wc];
#pragma unroll
      for (int ni = 0; ni < NI; ++ni) {
        float v = acc[mi][ni][i] + bv[ni];
        if (ACT == ACT_RELU) v = fmaxf(v, 0.f);
        crow[ni * 16 + fr] = v;
      }
    }
  }
}

// ---------------- fp32 GEMM (kept for W_dt, K=32) -------------------------
template <int BM, int BN, int BK, int TM, int TN, int ACT, bool BIAS>
__global__ __launch_bounds__(256) void gemm_f32(
    const float* __restrict__ A, int lda, const float* __restrict__ B,
    const float* __restrict__ bias, float* __restrict__ C, int M, int N, int K) {
  constexpr int TX = BN / TN;
  constexpr int TY = BM / TM;
  static_assert(TX * TY == 256, "bad cfg");
  __shared__ float As[BK][BM + 4];
  __shared__ float Bs[BK][BN];
  const int tid = threadIdx.x;
  const int tx = tid % TX, ty = tid / TX;
  const int bm = blockIdx.y * BM, bn = blockIdx.x * BN;
  float acc[TM][TN];
#pragma unroll
  for (int i = 0; i < TM; ++i)
#pragma unroll
    for (int j = 0; j < TN; ++j) acc[i][j] = 0.f;

  for (int k0 = 0; k0 < K; k0 += BK) {
#pragma unroll
    for (int i = tid; i < BM * BK / 4; i += 256) {
      int r = i / (BK / 4), c4 = i % (BK / 4);
      const float4 v = *(const float4*)&A[(size_t)(bm + r) * lda + k0 + c4 * 4];
      As[c4 * 4 + 0][r] = v.x;
      As[c4 * 4 + 1][r] = v.y;
      As[c4 * 4 + 2][r] = v.z;
      As[c4 * 4 + 3][r] = v.w;
    }
#pragma unroll
    for (int i = tid; i < BK * BN / 4; i += 256) {
      int r = i / (BN / 4), c4 = i % (BN / 4);
      *(float4*)&Bs[r][c4 * 4] = *(const float4*)&B[(size_t)(k0 + r) * N + bn + c4 * 4];
    }
    __syncthreads();
#pragma unroll
    for (int k = 0; k < BK; ++k) {
      float a[TM], b[TN];
#pragma unroll
      for (int i = 0; i < TM; i += 4) {
        const float4 t = *(const float4*)&As[k][ty * TM + i];
        a[i] = t.x; a[i + 1] = t.y; a[i + 2] = t.z; a[i + 3] = t.w;
      }
#pragma unroll
      for (int j = 0; j < TN; j += 4) {
        const float4 t = *(const float4*)&Bs[k][tx * TN + j];
        b[j] = t.x; b[j + 1] = t.y; b[j + 2] = t.z; b[j + 3] = t.w;
      }
#pragma unroll
      for (int i = 0; i < TM; ++i)
#pragma unroll
        for (int j = 0; j < TN; ++j) acc[i][j] = fmaf(a[i], b[j], acc[i][j]);
    }
    __syncthreads();
  }
#pragma unroll
  for (int i = 0; i < TM; ++i) {
    const int row = bm + ty * TM + i;
#pragma unroll
    for (int j = 0; j < TN; ++j) {
      float v = acc[i][j];
      if (BIAS) v += bias[bn + tx * TN + j];
      if (ACT == ACT_RELU) v = fmaxf(v, 0.f);
      if (ACT == ACT_SOFTPLUS) v = fmaxf(v, 0.f) + log1pf(expf(-fabsf(v)));
      acc[i][j] = v;
    }
#pragma unroll
    for (int j = 0; j < TN; j += 4) {
      float4 t;
      t.x = acc[i][j]; t.y = acc[i][j + 1]; t.z = acc[i][j + 2]; t.w = acc[i][j + 3];
      *(float4*)&C[(size_t)row * N + bn + tx * TN + j] = t;
    }
  }
}

// ---------------- depthwise causal conv (D_CONV=4) + bias + silu ----------
__global__ __launch_bounds__(256) void conv_silu_k(
    const float* __restrict__ xz, const float* __restrict__ Wc,
    const float* __restrict__ bc, float* __restrict__ xc) {
  const int idx = blockIdx.x * 256 + threadIdx.x;
  const int d = idx & (DINNER - 1);
  const int t = idx >> 10;
  const float4 w = *(const float4*)&Wc[d * 4];
  float acc = bc[d];
  if (t >= 3) acc = fmaf(w.x, xz[(size_t)(t - 3) * 2 * DINNER + d], acc);
  if (t >= 2) acc = fmaf(w.y, xz[(size_t)(t - 2) * 2 * DINNER + d], acc);
  if (t >= 1) acc = fmaf(w.z, xz[(size_t)(t - 1) * 2 * DINNER + d], acc);
  acc = fmaf(w.w, xz[(size_t)t * 2 * DINNER + d], acc);
  xc[idx] = siluf(acc);
}

// ---------------- skinny GEMM for W_x: 4096x1024 @ 1024x64 ----------------
__global__ __launch_bounds__(256) void gemm_skinny64(
    const float* __restrict__ A, const float* __restrict__ B, float* __restrict__ C) {
  __shared__ float As[8][DINNER];  // 32 KB
  const int tid = threadIdx.x;
  const int w = tid >> 6;
  const int lane = tid & 63;
  const int j4 = lane & 15;
  const int kk = lane >> 4;
  const int row0 = blockIdx.x * 8;
  for (int i = tid; i < 8 * (DINNER / 4); i += 256) {
    const int r = i >> 8, c = i & 255;
    *(float4*)&As[r][c * 4] = *(const float4*)&A[(size_t)(row0 + r) * DINNER + c * 4];
  }
  __syncthreads();
  const int r0 = w * 2;
  float4 acc0 = {0.f, 0.f, 0.f, 0.f}, acc1 = {0.f, 0.f, 0.f, 0.f};
#pragma unroll 4
  for (int k0 = 0; k0 < DINNER; k0 += 4) {
    const float4 b4 = *(const float4*)&B[(size_t)(k0 + kk) * 64 + j4 * 4];
    const float a0 = As[r0][k0 + kk];
    const float a1 = As[r0 + 1][k0 + kk];
    acc0.x = fmaf(a0, b4.x, acc0.x);
    acc0.y = fmaf(a0, b4.y, acc0.y);
    acc0.z = fmaf(a0, b4.z, acc0.z);
    acc0.w = fmaf(a0, b4.w, acc0.w);
    acc1.x = fmaf(a1, b4.x, acc1.x);
    acc1.y = fmaf(a1, b4.y, acc1.y);
    acc1.z = fmaf(a1, b4.z, acc1.z);
    acc1.w = fmaf(a1, b4.w, acc1.w);
  }
#pragma unroll
  for (int off = 16; off <= 32; off <<= 1) {
    acc0.x += __shfl_xor(acc0.x, off, 64);
    acc0.y += __shfl_xor(acc0.y, off, 64);
    acc0.z += __shfl_xor(acc0.z, off, 64);
    acc0.w += __shfl_xor(acc0.w, off, 64);
    acc1.x += __shfl_xor(acc1.x, off, 64);
    acc1.y += __shfl_xor(acc1.y, off, 64);
    acc1.z += __shfl_xor(acc1.z, off, 64);
    acc1.w += __shfl_xor(acc1.w, off, 64);
  }
  if (kk == 0) {
    *(float4*)&C[(size_t)(row0 + r0) * 64 + j4 * 4] = acc0;
    *(float4*)&C[(size_t)(row0 + r0 + 1) * 64 + j4 * 4] = acc1;
  }
}

// ---------------- LayerNorm (512 cols); optional residual; fp32/bf16 out --
template <bool BF16OUT>
__global__ __launch_bounds__(256) void layernorm_k(
    const float* __restrict__ x, const float* __restrict__ res,
    const float* __restrict__ w, const float* __restrict__ b, void* __restrict__ outp) {
  const int wave = threadIdx.x >> 6, lane = threadIdx.x & 63;
  const int row = blockIdx.x * 4 + wave;
  const size_t base = (size_t)row * DMODEL;
  float4 v0 = *(const float4*)&x[base + lane * 4];
  float4 v1 = *(const float4*)&x[base + 256 + lane * 4];
  if (res != nullptr) {
    const float4 r0 = *(const float4*)&res[base + lane * 4];
    const float4 r1 = *(const float4*)&res[base + 256 + lane * 4];
    v0.x += r0.x; v0.y += r0.y; v0.z += r0.z; v0.w += r0.w;
    v1.x += r1.x; v1.y += r1.y; v1.z += r1.z; v1.w += r1.w;
  }
  float s = (v0.x + v0.y) + (v0.z + v0.w) + (v1.x + v1.y) + (v1.z + v1.w);
  const float mean = wave_sum(s) * (1.f / DMODEL);
  const float d0 = v0.x - mean, d1 = v0.y - mean, d2 = v0.z - mean, d3 = v0.w - mean;
  const float d4 = v1.x - mean, d5 = v1.y - mean, d6 = v1.z - mean, d7 = v1.w - mean;
  float q = (d0 * d0 + d1 * d1) + (d2 * d2 + d3 * d3) + (d4 * d4 + d5 * d5) + (d6 * d6 + d7 * d7);
  const float rstd = rsqrtf(wave_sum(q) * (1.f / DMODEL) + 1e-5f);
  const float4 w0 = *(const float4*)&w[lane * 4];
  const float4 w1 = *(const float4*)&w[256 + lane * 4];
  const float4 b0 = *(const float4*)&b[lane * 4];
  const float4 b1 = *(const float4*)&b[256 + lane * 4];
  float o0 = fmaf(d0 * rstd, w0.x, b0.x), o1 = fmaf(d1 * rstd, w0.y, b0.y);
  float o2 = fmaf(d2 * rstd, w0.z, b0.z), o3 = fmaf(d3 * rstd, w0.w, b0.w);
  float o4 = fmaf(d4 * rstd, w1.x, b1.x), o5 = fmaf(d5 * rstd, w1.y, b1.y);
  float o6 = fmaf(d6 * rstd, w1.z, b1.z), o7 = fmaf(d7 * rstd, w1.w, b1.w);
  if (BF16OUT) {
    ushort* out = (ushort*)outp;
    ushort4 u0, u1;
    u0.x = f2bf(o0); u0.y = f2bf(o1); u0.z = f2bf(o2); u0.w = f2bf(o3);
    u1.x = f2bf(o4); u1.y = f2bf(o5); u1.z = f2bf(o6); u1.w = f2bf(o7);
    *(ushort4*)&out[base + lane * 4] = u0;
    *(ushort4*)&out[base + 256 + lane * 4] = u1;
  } else {
    float* out = (float*)outp;
    float4 f0, f1;
    f0.x = o0; f0.y = o1; f0.z = o2; f0.w = o3;
    f1.x = o4; f1.y = o5; f1.z = o6; f1.w = o7;
    *(float4*)&out[base + lane * 4] = f0;
    *(float4*)&out[base + 256 + lane * 4] = f1;
  }
}

// ---------------- selective scan: 3-phase chunked linear recurrence -------
__global__ __launch_bounds__(256) void scan_phaseA(
    const float* __restrict__ delta, const float* __restrict__ xc,
    const float* __restrict__ xdbl, const float* __restrict__ A_log,
    float* __restrict__ chA, float* __restrict__ chB) {
  const int chunk = blockIdx.x >> 2;
  const int d = ((blockIdx.x & 3) << 8) + threadIdx.x;
  __shared__ float Bsh[CHLEN][DSTATE];
  for (int i = threadIdx.x; i < CHLEN * DSTATE; i += 256) {
    const int t = i >> 4, s = i & 15;
    Bsh[t][s] = xdbl[(size_t)(chunk * CHLEN + t) * 64 + 32 + s];
  }
  __syncthreads();
  float Avl2[DSTATE];
#pragma unroll
  for (int s = 0; s < DSTATE; ++s)
    Avl2[s] = -expf(A_log[d * DSTATE + s]) * LOG2E;
  float aP[DSTATE], bP[DSTATE];
#pragma unroll
  for (int s = 0; s < DSTATE; ++s) { aP[s] = 1.f; bP[s] = 0.f; }
  const size_t col = (size_t)chunk * CHLEN * DINNER + d;
  for (int t0 = 0; t0 < CHLEN; t0 += 4) {
    float dl[4], du[4];
#pragma unroll
    for (int u = 0; u < 4; ++u) {
      const size_t idx = col + (size_t)(t0 + u) * DINNER;
      dl[u] = delta[idx];
      du[u] = dl[u] * xc[idx];
    }
#pragma unroll
    for (int u = 0; u < 4; ++u) {
#pragma unroll
      for (int s = 0; s < DSTATE; ++s) {
        const float a = exp2f(dl[u] * Avl2[s]);
        bP[s] = fmaf(a, bP[s], du[u] * Bsh[t0 + u][s]);
        aP[s] *= a;
      }
    }
  }
  const size_t base = (size_t)chunk * DINNER * DSTATE + (size_t)d * DSTATE;
#pragma unroll
  for (int s = 0; s < DSTATE; ++s) {
    chA[base + s] = aP[s];
    chB[base + s] = bP[s];
  }
}

// s0 may alias chB (in-place). 8-deep load batching hides memory latency.
__global__ __launch_bounds__(64) void scan_phaseB(
    const float* chA, const float* chB, float* s0) {
  const int i = blockIdx.x * 64 + threadIdx.x;
  float st = 0.f;
  for (int c0 = 0; c0 < NCHUNK; c0 += 8) {
    float a[8], b[8];
#pragma unroll
    for (int u = 0; u < 8; ++u) {
      const size_t idx = (size_t)(c0 + u) * (DINNER * DSTATE) + i;
      a[u] = chA[idx];
      b[u] = chB[idx];
    }
#pragma unroll
    for (int u = 0; u < 8; ++u) {
      const size_t idx = (size_t)(c0 + u) * (DINNER * DSTATE) + i;
      s0[idx] = st;
      st = fmaf(a[u], st, b[u]);
    }
  }
}

__global__ __launch_bounds__(256) void scan_phaseC(
    const float* __restrict__ delta, const float* __restrict__ xc,
    const float* __restrict__ xdbl, const float* __restrict__ A_log,
    const float* __restrict__ Dsk, const float* __restrict__ s0,
    const float* __restrict__ xz, ushort* __restrict__ y) {
  const int chunk = blockIdx.x >> 2;
  const int d = ((blockIdx.x & 3) << 8) + threadIdx.x;
  __shared__ float BCsh[CHLEN][2 * DSTATE];
  for (int i = threadIdx.x; i < CHLEN * 2 * DSTATE; i += 256) {
    const int t = i >> 5, s = i & 31;
    BCsh[t][s] = xdbl[(size_t)(chunk * CHLEN + t) * 64 + 32 + s];
  }
  __syncthreads();
  float Avl2[DSTATE];
#pragma unroll
  for (int s = 0; s < DSTATE; ++s)
    Avl2[s] = -expf(A_log[d * DSTATE + s]) * LOG2E;
  float st[DSTATE];
  const size_t base = (size_t)chunk * DINNER * DSTATE + (size_t)d * DSTATE;
#pragma unroll
  for (int s = 0; s < DSTATE; ++s) st[s] = s0[base + s];
  const float Dv = Dsk[d];
  const size_t col = (size_t)chunk * CHLEN * DINNER + d;
  const size_t zcol = (size_t)chunk * CHLEN * 2 * DINNER + DINNER + d;
  for (int t0 = 0; t0 < CHLEN; t0 += 4) {
    float dl[4], xv[4], zv[4];
#pragma unroll
    for (int u = 0; u < 4; ++u) {
      const size_t idx = col + (size_t)(t0 + u) * DINNER;
      dl[u] = delta[idx];
      xv[u] = xc[idx];
      zv[u] = xz[zcol + (size_t)(t0 + u) * 2 * DINNER];
    }
    ushort yo[4];
#pragma unroll
    for (int u = 0; u < 4; ++u) {
      const float du = dl[u] * xv[u];
      float yv = 0.f;
#pragma unroll
      for (int s = 0; s < DSTATE; ++s) {
        const float a = exp2f(dl[u] * Avl2[s]);
        st[s] = fmaf(a, st[s], du * BCsh[t0 + u][s]);
        yv = fmaf(st[s], BCsh[t0 + u][DSTATE + s], yv);
      }
      yo[u] = f2bf((yv + xv[u] * Dv) * siluf(zv[u]));
    }
#pragma unroll
    for (int u = 0; u < 4; ++u)
      y[col + (size_t)(t0 + u) * DINNER] = yo[u];
  }
}

// ---------------- attention scores: tanh(h@Wa1+ba1)@Wa2+ba2 ---------------
__global__ __launch_bounds__(256) void attn_scores_k(
    const float* __restrict__ h, const float* __restrict__ Wa1,
    const float* __restrict__ ba1, const float* __restrict__ Wa2,
    const float* __restrict__ ba2, float* __restrict__ scores) {
  __shared__ float hs[8][DMODEL];
  __shared__ float part[8][2][ATTH];
  __shared__ float red[8][2];
  const int tid = threadIdx.x;
  const int j = tid & 127;
  const int half = tid >> 7;
  const int t0 = blockIdx.x * 8;
  for (int i = tid; i < 8 * DMODEL / 4; i += 256) {
    const int rr = i >> 7, cc = i & 127;
    *(float4*)&hs[rr][cc * 4] = *(const float4*)&h[(size_t)(t0 + rr) * DMODEL + cc * 4];
  }
  __syncthreads();
  float acc[8];
#pragma unroll
  for (int rr = 0; rr < 8; ++rr) acc[rr] = 0.f;
  const int kbase = half * 256;
  for (int k0 = 0; k0 < 256; k0 += 4) {
    float wv[4];
#pragma unroll
    for (int u = 0; u < 4; ++u)
      wv[u] = Wa1[(size_t)(kbase + k0 + u) * ATTH + j];
#pragma unroll
    for (int rr = 0; rr < 8; ++rr) {
      const float4 hv = *(const float4*)&hs[rr][kbase + k0];
      acc[rr] = fmaf(hv.x, wv[0], acc[rr]);
      acc[rr] = fmaf(hv.y, wv[1], acc[rr]);
      acc[rr] = fmaf(hv.z, wv[2], acc[rr]);
      acc[rr] = fmaf(hv.w, wv[3], acc[rr]);
    }
  }
#pragma unroll
  for (int rr = 0; rr < 8; ++rr) part[rr][half][j] = acc[rr];
  __syncthreads();
  if (half == 0) {
    const float w2 = Wa2[j];
    const float b1 = ba1[j];
    const int wv_ = j >> 6;
#pragma unroll
    for (int rr = 0; rr < 8; ++rr) {
      float v = tanhf(part[rr][0][j] + part[rr][1][j] + b1) * w2;
      v = wave_sum(v);
      if ((j & 63) == 0) red[rr][wv_] = v;
    }
  }
  __syncthreads();
  if (tid < 8) scores[t0 + tid] = red[tid][0] + red[tid][1] + ba2[0];
}

__global__ __launch_bounds__(1024) void softmax_k(
    const float* __restrict__ s, float* __restrict__ aw) {
  const int tid = threadIdx.x;
  const int wave = tid >> 6, lane = tid & 63;
  const float4 v = *(const float4*)&s[tid * 4];
  float m = fmaxf(fmaxf(v.x, v.y), fmaxf(v.z, v.w));
  m = wave_max(m);
  __shared__ float redm[16];
  if (lane == 0) redm[wave] = m;
  __syncthreads();
  float bm = redm[0];
#pragma unroll
  for (int i = 1; i < 16; ++i) bm = fmaxf(bm, redm[i]);
  const float e0 = expf(v.x - bm), e1 = expf(v.y - bm);
  const float e2 = expf(v.z - bm), e3 = expf(v.w - bm);
  float sum = wave_sum((e0 + e1) + (e2 + e3));
  __shared__ float reds[16];
  if (lane == 0) reds[wave] = sum;
  __syncthreads();
  float Z = 0.f;
#pragma unroll
  for (int i = 0; i < 16; ++i) Z += reds[i];
  const float inv = 1.f / Z;
  float4 o;
  o.x = e0 * inv; o.y = e1 * inv; o.z = e2 * inv; o.w = e3 * inv;
  *(float4*)&aw[tid * 4] = o;
}

__global__ __launch_bounds__(256) void pool_partial_k(
    const float* __restrict__ aw, const float* __restrict__ h, float* __restrict__ part) {
  const int b = blockIdx.x;
  const int tid = threadIdx.x;
  float2 acc = make_float2(0.f, 0.f);
  for (int t = b * 64; t < b * 64 + 64; ++t) {
    const float w = aw[t];
    const float2 hv = *(const float2*)&h[(size_t)t * DMODEL + tid * 2];
    acc.x = fmaf(w, hv.x, acc.x);
    acc.y = fmaf(w, hv.y, acc.y);
  }
  *(float2*)&part[b * DMODEL + tid * 2] = acc;
}

__global__ __launch_bounds__(512) void pool_final_k(
    const float* __restrict__ part, const float* __restrict__ Wh,
    const float* __restrict__ bh, float* __restrict__ out) {
  const int d = threadIdx.x;
  float s = 0.f;
  for (int b = 0; b < 64; ++b) s += part[b * DMODEL + d];
  float v0 = wave_sum(s * Wh[d * 2 + 0]);
  float v1 = wave_sum(s * Wh[d * 2 + 1]);
  __shared__ float r0[8], r1[8];
  const int wave = d >> 6, lane = d & 63;
  if (lane == 0) { r0[wave] = v0; r1[wave] = v1; }
  __syncthreads();
  if (d == 0) {
    float o0 = bh[0], o1 = bh[1];
#pragma unroll
    for (int i = 0; i < 8; ++i) { o0 += r0[i]; o1 += r1[i]; }
    out[0] = o0;
    out[1] = o1;
  }
}

extern "C" void kernel_launch(void* const* d_in, const int* in_sizes, int n_in,
                              void* d_out, int out_size, void* d_ws, size_t ws_size,
                              hipStream_t stream) {
  const float* in_h = (const float*)d_in[0];
  const float* W_proj = (const float*)d_in[1];
  const float* b_proj = (const float*)d_in[2];
  const float* ln_w = (const float*)d_in[3];
  const float* ln_b = (const float*)d_in[4];
  const float* W_in = (const float*)d_in[5];
  const float* W_conv = (const float*)d_in[6];
  const float* b_conv = (const float*)d_in[7];
  const float* W_x = (const float*)d_in[8];
  const float* W_dt = (const float*)d_in[9];
  const float* b_dt = (const float*)d_in[10];
  const float* A_log = (const float*)d_in[11];
  const float* Dsk = (const float*)d_in[12];
  const float* W_out = (const float*)d_in[13];
  const float* norm_w = (const float*)d_in[14];
  const float* norm_b = (const float*)d_in[15];
  const float* Wa1 = (const float*)d_in[16];
  const float* ba1 = (const float*)d_in[17];
  const float* Wa2 = (const float*)d_in[18];
  const float* ba2 = (const float*)d_in[19];
  const float* Wh = (const float*)d_in[20];
  const float* bh = (const float*)d_in[21];
  float* out = (float*)d_out;

  float* ws = (float*)d_ws;
  size_t off = 0;
  auto alloc = [&](size_t n) {
    float* p = ws + off;
    off += (n + 63) & ~(size_t)63;
    return p;
  };
  float* res = alloc((size_t)LSEQ * DMODEL);
  float* hbuf = alloc((size_t)LSEQ * DMODEL);
  float* xz = alloc((size_t)LSEQ * 2 * DINNER);
  float* xc = alloc((size_t)LSEQ * DINNER);
  float* xdbl = alloc((size_t)LSEQ * 64);
  float* delta = alloc((size_t)LSEQ * DINNER);
  float* chA = alloc((size_t)DINNER * DSTATE * NCHUNK);
  float* chB = alloc((size_t)DINNER * DSTATE * NCHUNK);
  ushort* lnb_bf = (ushort*)alloc((size_t)LSEQ * DMODEL / 2);
  ushort* y_bf = (ushort*)alloc((size_t)LSEQ * DINNER / 2);
  ushort* in_bf = (ushort*)alloc((size_t)LSEQ * 1024 / 2);
  ushort* WprojT = (ushort*)alloc((size_t)DMODEL * 1024 / 2);
  ushort* W_inT = (ushort*)alloc((size_t)2 * 2048 * 512 / 2);
  ushort* W_outT = (ushort*)alloc((size_t)2 * 512 * 1024 / 2);
  (void)ws_size;
  float* s0b = chB;  // phaseB writes prefix-state in-place over chB
  float* hfin = xz;
  float* scores = xz + (size_t)LSEQ * DMODEL;
  float* aw = scores + LSEQ;
  float* part = aw + LSEQ;

  // 0. one-shot prep: input cast + all 5 weight transposes
  prep_k<<<5632, 256, 0, stream>>>(in_h, in_bf, W_proj, WprojT, W_in, W_inT,
                                   W_out, W_outT);
  // 1. proj GEMM (relu+bias) -> res
  gemm_bf16<64, 128, ACT_RELU, true>
      <<<dim3(DMODEL / 128, LSEQ / 64), 256, 0, stream>>>(
          in_bf, WprojT, b_proj, res, LSEQ, DMODEL, 1024);

  const float* cur = res;
  for (int l = 0; l < 2; ++l) {
    layernorm_k<true><<<LSEQ / 4, 256, 0, stream>>>(
        cur, nullptr, ln_w + l * DMODEL, ln_b + l * DMODEL, lnb_bf);
    gemm_bf16<128, 128, ACT_NONE, false>
        <<<dim3(2 * DINNER / 128, LSEQ / 128), 256, 0, stream>>>(
            lnb_bf, W_inT + (size_t)l * 2048 * 512, nullptr, xz, LSEQ,
            2 * DINNER, DMODEL);
    conv_silu_k<<<LSEQ * DINNER / 256, 256, 0, stream>>>(
        xz, W_conv + l * DINNER * 4, b_conv + l * DINNER, xc);
    gemm_skinny64<<<LSEQ / 8, 256, 0, stream>>>(
        xc, W_x + (size_t)l * DINNER * 64, xdbl);
    gemm_f32<128, 128, 16, 8, 8, ACT_SOFTPLUS, true>
        <<<dim3(DINNER / 128, LSEQ / 128), 256, 0, stream>>>(
            xdbl, 64, W_dt + (size_t)l * DTRANK * DINNER, b_dt + l * DINNER,
            delta, LSEQ, DINNER, DTRANK);
    const float* Al = A_log + (size_t)l * DINNER * DSTATE;
    scan_phaseA<<<NCHUNK * 4, 256, 0, stream>>>(delta, xc, xdbl, Al, chA, chB);
    scan_phaseB<<<DINNER * DSTATE / 64, 64, 0, stream>>>(chA, chB, s0b);
    scan_phaseC<<<NCHUNK * 4, 256, 0, stream>>>(
        delta, xc, xdbl, Al, Dsk + l * DINNER, s0b, xz, y_bf);
    gemm_bf16<64, 128, ACT_NONE, false>
        <<<dim3(DMODEL / 128, LSEQ / 64), 256, 0, stream>>>(
            y_bf, W_outT + (size_t)l * 512 * 1024, nullptr, hbuf, LSEQ, DMODEL,
            DINNER);
    cur = hbuf;
  }

  layernorm_k<false><<<LSEQ / 4, 256, 0, stream>>>(cur, res, norm_w, norm_b, hfin);
  attn_scores_k<<<LSEQ / 8, 256, 0, stream>>>(hfin, Wa1, ba1, Wa2, ba2, scores);
  softmax_k<<<1, 1024, 0, stream>>>(scores, aw);
  pool_partial_k<<<64, 256, 0, stream>>>(aw, hfin, part);
  pool_final_k<<<1, 512, 0, stream>>>(part, Wh, bh, out);
}

// Round 15
// 424.762 us; speedup vs baseline: 1.0265x; 1.0050x over previous
//
#include <hip/hip_runtime.h>
#include <math.h>

// MambaMIL: bf16-MFMA GEMMs + fp32 scan.
// R15: REVERT R14's cooperative fused scan (FAILED: absmax 2.4e-4; grid.sync
//      does not guarantee cross-XCD visibility of plain stores -> stale chA/chB
//      reads; fix would need L2-flush fences costing the predicted win).
//      Restored R13 = best known (426us, absmax 6.1e-5).

#define LSEQ 4096
#define DMODEL 512
#define DINNER 1024
#define DSTATE 16
#define DTRANK 32
#define NCHUNK 256
#define CHLEN 16
#define ATTH 128
#define LOG2E 1.4426950408889634f

enum { ACT_NONE = 0, ACT_RELU = 1, ACT_SOFTPLUS = 2 };

typedef __attribute__((ext_vector_type(8))) short bf16x8;
typedef __attribute__((ext_vector_type(4))) float f32x4;
using gas1 = const __attribute__((address_space(1))) void;
using las3 = __attribute__((address_space(3))) void;

__device__ __forceinline__ float wave_sum(float v) {
#pragma unroll
  for (int off = 32; off > 0; off >>= 1) v += __shfl_xor(v, off, 64);
  return v;
}
__device__ __forceinline__ float wave_max(float v) {
#pragma unroll
  for (int off = 32; off > 0; off >>= 1) v = fmaxf(v, __shfl_xor(v, off, 64));
  return v;
}
__device__ __forceinline__ float siluf(float x) {
  return x * __builtin_amdgcn_rcpf(1.f + exp2f(-LOG2E * x));
}

__device__ __forceinline__ ushort f2bf(float f) {
  union { float f; unsigned u; } c;
  c.f = f;
  return (ushort)((c.u + 0x7FFFu + ((c.u >> 16) & 1u)) >> 16);
}

// ---------------- prep: input cast + all weight transposes ----------------
__global__ __launch_bounds__(256) void prep_k(
    const float* __restrict__ in_h, ushort* __restrict__ in_bf,
    const float* __restrict__ W_proj, ushort* __restrict__ WprojT,
    const float* __restrict__ W_in, ushort* __restrict__ W_inT,
    const float* __restrict__ W_out, ushort* __restrict__ W_outT) {
  __shared__ float tbuf[32][33];
  const int b = blockIdx.x;
  if (b < 2048) {
    const size_t i = ((size_t)b * 256 + threadIdx.x) * 8;
    const float4 a = *(const float4*)&in_h[i];
    const float4 c = *(const float4*)&in_h[i + 4];
    ushort4 o0, o1;
    o0.x = f2bf(a.x); o0.y = f2bf(a.y); o0.z = f2bf(a.z); o0.w = f2bf(a.w);
    o1.x = f2bf(c.x); o1.y = f2bf(c.y); o1.z = f2bf(c.z); o1.w = f2bf(c.w);
    *(ushort4*)&in_bf[i] = o0;
    *(ushort4*)&in_bf[i + 4] = o1;
    return;
  }
  int t = b - 2048;
  const float* src;
  ushort* dst;
  int K, N;
  if (t < 512) {
    src = W_proj; dst = WprojT; K = 1024; N = 512;
  } else if (t < 512 + 1024) {
    t -= 512; src = W_in; dst = W_inT; K = 512; N = 2048;
  } else if (t < 512 + 2048) {
    t -= 512 + 1024; src = W_in + (size_t)512 * 2048; dst = W_inT + (size_t)2048 * 512;
    K = 512; N = 2048;
  } else if (t < 512 + 2048 + 512) {
    t -= 512 + 2048; src = W_out; dst = W_outT; K = 1024; N = 512;
  } else {
    t -= 512 + 2048 + 512; src = W_out + (size_t)1024 * 512; dst = W_outT + (size_t)512 * 1024;
    K = 1024; N = 512;
  }
  const int tiles_x = N / 32;
  const int n0 = (t % tiles_x) * 32, k0 = (t / tiles_x) * 32;
  const int tx = threadIdx.x & 31, ty = threadIdx.x >> 5;
#pragma unroll
  for (int i = 0; i < 32; i += 8)
    tbuf[ty + i][tx] = src[(size_t)(k0 + ty + i) * N + n0 + tx];
  __syncthreads();
#pragma unroll
  for (int i = 0; i < 32; i += 8)
    dst[(size_t)(n0 + ty + i) * K + k0 + tx] = f2bf(tbuf[tx][ty + i]);
}

// ---------------- bf16 MFMA GEMM: C = act(A @ Bt^T + bias) ----------------
template <int BM, int BN, int ACT, bool BIAS>
__global__ __launch_bounds__(256) void gemm_bf16(
    const ushort* __restrict__ A, const ushort* __restrict__ Bt,
    const float* __restrict__ bias, float* __restrict__ C, int M, int N, int K) {
  constexpr int MI = BM / 32;
  constexpr int NI = BN / 32;
  __shared__ __align__(16) ushort As[BM][32];
  __shared__ __align__(16) ushort Bs[BN][32];
  const int tid = threadIdx.x;
  const int lane = tid & 63;
  const int w = tid >> 6;
  const int wr = (w >> 1) * (BM / 2), wc = (w & 1) * (BN / 2);
  const int fr = lane & 15;
  const int kg = lane >> 4;
  const int bm = blockIdx.y * BM, bn = blockIdx.x * BN;
  const int srow = lane >> 2;
  const int sg = lane & 3;

  f32x4 acc[MI][NI];
#pragma unroll
  for (int i = 0; i < MI; ++i)
#pragma unroll
    for (int j = 0; j < NI; ++j) acc[i][j] = (f32x4){0.f, 0.f, 0.f, 0.f};

  for (int k0 = 0; k0 < K; k0 += 32) {
#pragma unroll
    for (int c = 0; c < BM / 64; ++c) {
      const int row = c * 64 + w * 16 + srow;
      const int g = sg ^ ((row >> 1) & 3);
      __builtin_amdgcn_global_load_lds(
          (gas1*)(A + (size_t)(bm + row) * K + k0 + g * 8),
          (las3*)&As[c * 64 + w * 16][0], 16, 0, 0);
    }
#pragma unroll
    for (int c = 0; c < BN / 64; ++c) {
      const int row = c * 64 + w * 16 + srow;
      const int g = sg ^ ((row >> 1) & 3);
      __builtin_amdgcn_global_load_lds(
          (gas1*)(Bt + (size_t)(bn + row) * K + k0 + g * 8),
          (las3*)&Bs[c * 64 + w * 16][0], 16, 0, 0);
    }
    __syncthreads();
    bf16x8 a[MI], b[NI];
#pragma unroll
    for (int mi = 0; mi < MI; ++mi) {
      const int r = wr + mi * 16 + fr;
      a[mi] = *(const bf16x8*)&As[r][(kg ^ ((r >> 1) & 3)) * 8];
    }
#pragma unroll
    for (int ni = 0; ni < NI; ++ni) {
      const int r = wc + ni * 16 + fr;
      b[ni] = *(const bf16x8*)&Bs[r][(kg ^ ((r >> 1) & 3)) * 8];
    }
#pragma unroll
    for (int mi = 0; mi < MI; ++mi)
#pragma unroll
      for (int ni = 0; ni < NI; ++ni)
        acc[mi][ni] = __builtin_amdgcn_mfma_f32_16x16x32_bf16(
            a[mi], b[ni], acc[mi][ni], 0, 0, 0);
    __syncthreads();
  }

  float bv[NI];
#pragma unroll
  for (int ni = 0; ni < NI; ++ni) bv[ni] = BIAS ? bias[bn + wc + ni * 16 + fr] : 0.f;
#pragma unroll
  for (int mi = 0; mi < MI; ++mi) {
#pragma unroll
    for (int i = 0; i < 4; ++i) {
      const int row = bm + wr + mi * 16 + kg * 4 + i;
      float* crow = &C[(size_t)row * N + bn + wc];
#pragma unroll
      for (int ni = 0; ni < NI; ++ni) {
        float v = acc[mi][ni][i] + bv[ni];
        if (ACT == ACT_RELU) v = fmaxf(v, 0.f);
        crow[ni * 16 + fr] = v;
      }
    }
  }
}

// ---------------- fp32 GEMM (kept for W_dt, K=32) -------------------------
template <int BM, int BN, int BK, int TM, int TN, int ACT, bool BIAS>
__global__ __launch_bounds__(256) void gemm_f32(
    const float* __restrict__ A, int lda, const float* __restrict__ B,
    const float* __restrict__ bias, float* __restrict__ C, int M, int N, int K) {
  constexpr int TX = BN / TN;
  constexpr int TY = BM / TM;
  static_assert(TX * TY == 256, "bad cfg");
  __shared__ float As[BK][BM + 4];
  __shared__ float Bs[BK][BN];
  const int tid = threadIdx.x;
  const int tx = tid % TX, ty = tid / TX;
  const int bm = blockIdx.y * BM, bn = blockIdx.x * BN;
  float acc[TM][TN];
#pragma unroll
  for (int i = 0; i < TM; ++i)
#pragma unroll
    for (int j = 0; j < TN; ++j) acc[i][j] = 0.f;

  for (int k0 = 0; k0 < K; k0 += BK) {
#pragma unroll
    for (int i = tid; i < BM * BK / 4; i += 256) {
      int r = i / (BK / 4), c4 = i % (BK / 4);
      const float4 v = *(const float4*)&A[(size_t)(bm + r) * lda + k0 + c4 * 4];
      As[c4 * 4 + 0][r] = v.x;
      As[c4 * 4 + 1][r] = v.y;
      As[c4 * 4 + 2][r] = v.z;
      As[c4 * 4 + 3][r] = v.w;
    }
#pragma unroll
    for (int i = tid; i < BK * BN / 4; i += 256) {
      int r = i / (BN / 4), c4 = i % (BN / 4);
      *(float4*)&Bs[r][c4 * 4] = *(const float4*)&B[(size_t)(k0 + r) * N + bn + c4 * 4];
    }
    __syncthreads();
#pragma unroll
    for (int k = 0; k < BK; ++k) {
      float a[TM], b[TN];
#pragma unroll
      for (int i = 0; i < TM; i += 4) {
        const float4 t = *(const float4*)&As[k][ty * TM + i];
        a[i] = t.x; a[i + 1] = t.y; a[i + 2] = t.z; a[i + 3] = t.w;
      }
#pragma unroll
      for (int j = 0; j < TN; j += 4) {
        const float4 t = *(const float4*)&Bs[k][tx * TN + j];
        b[j] = t.x; b[j + 1] = t.y; b[j + 2] = t.z; b[j + 3] = t.w;
      }
#pragma unroll
      for (int i = 0; i < TM; ++i)
#pragma unroll
        for (int j = 0; j < TN; ++j) acc[i][j] = fmaf(a[i], b[j], acc[i][j]);
    }
    __syncthreads();
  }
#pragma unroll
  for (int i = 0; i < TM; ++i) {
    const int row = bm + ty * TM + i;
#pragma unroll
    for (int j = 0; j < TN; ++j) {
      float v = acc[i][j];
      if (BIAS) v += bias[bn + tx * TN + j];
      if (ACT == ACT_RELU) v = fmaxf(v, 0.f);
      if (ACT == ACT_SOFTPLUS) v = fmaxf(v, 0.f) + log1pf(expf(-fabsf(v)));
      acc[i][j] = v;
    }
#pragma unroll
    for (int j = 0; j < TN; j += 4) {
      float4 t;
      t.x = acc[i][j]; t.y = acc[i][j + 1]; t.z = acc[i][j + 2]; t.w = acc[i][j + 3];
      *(float4*)&C[(size_t)row * N + bn + tx * TN + j] = t;
    }
  }
}

// ---------------- depthwise causal conv (D_CONV=4) + bias + silu ----------
__global__ __launch_bounds__(256) void conv_silu_k(
    const float* __restrict__ xz, const float* __restrict__ Wc,
    const float* __restrict__ bc, float* __restrict__ xc) {
  const int idx = blockIdx.x * 256 + threadIdx.x;
  const int d = idx & (DINNER - 1);
  const int t = idx >> 10;
  const float4 w = *(const float4*)&Wc[d * 4];
  float acc = bc[d];
  if (t >= 3) acc = fmaf(w.x, xz[(size_t)(t - 3) * 2 * DINNER + d], acc);
  if (t >= 2) acc = fmaf(w.y, xz[(size_t)(t - 2) * 2 * DINNER + d], acc);
  if (t >= 1) acc = fmaf(w.z, xz[(size_t)(t - 1) * 2 * DINNER + d], acc);
  acc = fmaf(w.w, xz[(size_t)t * 2 * DINNER + d], acc);
  xc[idx] = siluf(acc);
}

// ---------------- skinny GEMM for W_x: 4096x1024 @ 1024x64 ----------------
__global__ __launch_bounds__(256) void gemm_skinny64(
    const float* __restrict__ A, const float* __restrict__ B, float* __restrict__ C) {
  __shared__ float As[8][DINNER];  // 32 KB
  const int tid = threadIdx.x;
  const int w = tid >> 6;
  const int lane = tid & 63;
  const int j4 = lane & 15;
  const int kk = lane >> 4;
  const int row0 = blockIdx.x * 8;
  for (int i = tid; i < 8 * (DINNER / 4); i += 256) {
    const int r = i >> 8, c = i & 255;
    *(float4*)&As[r][c * 4] = *(const float4*)&A[(size_t)(row0 + r) * DINNER + c * 4];
  }
  __syncthreads();
  const int r0 = w * 2;
  float4 acc0 = {0.f, 0.f, 0.f, 0.f}, acc1 = {0.f, 0.f, 0.f, 0.f};
#pragma unroll 4
  for (int k0 = 0; k0 < DINNER; k0 += 4) {
    const float4 b4 = *(const float4*)&B[(size_t)(k0 + kk) * 64 + j4 * 4];
    const float a0 = As[r0][k0 + kk];
    const float a1 = As[r0 + 1][k0 + kk];
    acc0.x = fmaf(a0, b4.x, acc0.x);
    acc0.y = fmaf(a0, b4.y, acc0.y);
    acc0.z = fmaf(a0, b4.z, acc0.z);
    acc0.w = fmaf(a0, b4.w, acc0.w);
    acc1.x = fmaf(a1, b4.x, acc1.x);
    acc1.y = fmaf(a1, b4.y, acc1.y);
    acc1.z = fmaf(a1, b4.z, acc1.z);
    acc1.w = fmaf(a1, b4.w, acc1.w);
  }
#pragma unroll
  for (int off = 16; off <= 32; off <<= 1) {
    acc0.x += __shfl_xor(acc0.x, off, 64);
    acc0.y += __shfl_xor(acc0.y, off, 64);
    acc0.z += __shfl_xor(acc0.z, off, 64);
    acc0.w += __shfl_xor(acc0.w, off, 64);
    acc1.x += __shfl_xor(acc1.x, off, 64);
    acc1.y += __shfl_xor(acc1.y, off, 64);
    acc1.z += __shfl_xor(acc1.z, off, 64);
    acc1.w += __shfl_xor(acc1.w, off, 64);
  }
  if (kk == 0) {
    *(float4*)&C[(size_t)(row0 + r0) * 64 + j4 * 4] = acc0;
    *(float4*)&C[(size_t)(row0 + r0 + 1) * 64 + j4 * 4] = acc1;
  }
}

// ---------------- LayerNorm (512 cols); optional residual; fp32/bf16 out --
template <bool BF16OUT>
__global__ __launch_bounds__(256) void layernorm_k(
    const float* __restrict__ x, const float* __restrict__ res,
    const float* __restrict__ w, const float* __restrict__ b, void* __restrict__ outp) {
  const int wave = threadIdx.x >> 6, lane = threadIdx.x & 63;
  const int row = blockIdx.x * 4 + wave;
  const size_t base = (size_t)row * DMODEL;
  float4 v0 = *(const float4*)&x[base + lane * 4];
  float4 v1 = *(const float4*)&x[base + 256 + lane * 4];
  if (res != nullptr) {
    const float4 r0 = *(const float4*)&res[base + lane * 4];
    const float4 r1 = *(const float4*)&res[base + 256 + lane * 4];
    v0.x += r0.x; v0.y += r0.y; v0.z += r0.z; v0.w += r0.w;
    v1.x += r1.x; v1.y += r1.y; v1.z += r1.z; v1.w += r1.w;
  }
  float s = (v0.x + v0.y) + (v0.z + v0.w) + (v1.x + v1.y) + (v1.z + v1.w);
  const float mean = wave_sum(s) * (1.f / DMODEL);
  const float d0 = v0.x - mean, d1 = v0.y - mean, d2 = v0.z - mean, d3 = v0.w - mean;
  const float d4 = v1.x - mean, d5 = v1.y - mean, d6 = v1.z - mean, d7 = v1.w - mean;
  float q = (d0 * d0 + d1 * d1) + (d2 * d2 + d3 * d3) + (d4 * d4 + d5 * d5) + (d6 * d6 + d7 * d7);
  const float rstd = rsqrtf(wave_sum(q) * (1.f / DMODEL) + 1e-5f);
  const float4 w0 = *(const float4*)&w[lane * 4];
  const float4 w1 = *(const float4*)&w[256 + lane * 4];
  const float4 b0 = *(const float4*)&b[lane * 4];
  const float4 b1 = *(const float4*)&b[256 + lane * 4];
  float o0 = fmaf(d0 * rstd, w0.x, b0.x), o1 = fmaf(d1 * rstd, w0.y, b0.y);
  float o2 = fmaf(d2 * rstd, w0.z, b0.z), o3 = fmaf(d3 * rstd, w0.w, b0.w);
  float o4 = fmaf(d4 * rstd, w1.x, b1.x), o5 = fmaf(d5 * rstd, w1.y, b1.y);
  float o6 = fmaf(d6 * rstd, w1.z, b1.z), o7 = fmaf(d7 * rstd, w1.w, b1.w);
  if (BF16OUT) {
    ushort* out = (ushort*)outp;
    ushort4 u0, u1;
    u0.x = f2bf(o0); u0.y = f2bf(o1); u0.z = f2bf(o2); u0.w = f2bf(o3);
    u1.x = f2bf(o4); u1.y = f2bf(o5); u1.z = f2bf(o6); u1.w = f2bf(o7);
    *(ushort4*)&out[base + lane * 4] = u0;
    *(ushort4*)&out[base + 256 + lane * 4] = u1;
  } else {
    float* out = (float*)outp;
    float4 f0, f1;
    f0.x = o0; f0.y = o1; f0.z = o2; f0.w = o3;
    f1.x = o4; f1.y = o5; f1.z = o6; f1.w = o7;
    *(float4*)&out[base + lane * 4] = f0;
    *(float4*)&out[base + 256 + lane * 4] = f1;
  }
}

// ---------------- selective scan: 3-phase chunked linear recurrence -------
__global__ __launch_bounds__(256) void scan_phaseA(
    const float* __restrict__ delta, const float* __restrict__ xc,
    const float* __restrict__ xdbl, const float* __restrict__ A_log,
    float* __restrict__ chA, float* __restrict__ chB) {
  const int chunk = blockIdx.x >> 2;
  const int d = ((blockIdx.x & 3) << 8) + threadIdx.x;
  __shared__ float Bsh[CHLEN][DSTATE];
  for (int i = threadIdx.x; i < CHLEN * DSTATE; i += 256) {
    const int t = i >> 4, s = i & 15;
    Bsh[t][s] = xdbl[(size_t)(chunk * CHLEN + t) * 64 + 32 + s];
  }
  __syncthreads();
  float Avl2[DSTATE];
#pragma unroll
  for (int s = 0; s < DSTATE; ++s)
    Avl2[s] = -expf(A_log[d * DSTATE + s]) * LOG2E;
  float aP[DSTATE], bP[DSTATE];
#pragma unroll
  for (int s = 0; s < DSTATE; ++s) { aP[s] = 1.f; bP[s] = 0.f; }
  const size_t col = (size_t)chunk * CHLEN * DINNER + d;
  for (int t0 = 0; t0 < CHLEN; t0 += 4) {
    float dl[4], du[4];
#pragma unroll
    for (int u = 0; u < 4; ++u) {
      const size_t idx = col + (size_t)(t0 + u) * DINNER;
      dl[u] = delta[idx];
      du[u] = dl[u] * xc[idx];
    }
#pragma unroll
    for (int u = 0; u < 4; ++u) {
#pragma unroll
      for (int s = 0; s < DSTATE; ++s) {
        const float a = exp2f(dl[u] * Avl2[s]);
        bP[s] = fmaf(a, bP[s], du[u] * Bsh[t0 + u][s]);
        aP[s] *= a;
      }
    }
  }
  const size_t base = (size_t)chunk * DINNER * DSTATE + (size_t)d * DSTATE;
#pragma unroll
  for (int s = 0; s < DSTATE; ++s) {
    chA[base + s] = aP[s];
    chB[base + s] = bP[s];
  }
}

// s0 may alias chB (in-place). 8-deep load batching hides memory latency.
__global__ __launch_bounds__(64) void scan_phaseB(
    const float* chA, const float* chB, float* s0) {
  const int i = blockIdx.x * 64 + threadIdx.x;
  float st = 0.f;
  for (int c0 = 0; c0 < NCHUNK; c0 += 8) {
    float a[8], b[8];
#pragma unroll
    for (int u = 0; u < 8; ++u) {
      const size_t idx = (size_t)(c0 + u) * (DINNER * DSTATE) + i;
      a[u] = chA[idx];
      b[u] = chB[idx];
    }
#pragma unroll
    for (int u = 0; u < 8; ++u) {
      const size_t idx = (size_t)(c0 + u) * (DINNER * DSTATE) + i;
      s0[idx] = st;
      st = fmaf(a[u], st, b[u]);
    }
  }
}

__global__ __launch_bounds__(256) void scan_phaseC(
    const float* __restrict__ delta, const float* __restrict__ xc,
    const float* __restrict__ xdbl, const float* __restrict__ A_log,
    const float* __restrict__ Dsk, const float* __restrict__ s0,
    const float* __restrict__ xz, ushort* __restrict__ y) {
  const int chunk = blockIdx.x >> 2;
  const int d = ((blockIdx.x & 3) << 8) + threadIdx.x;
  __shared__ float BCsh[CHLEN][2 * DSTATE];
  for (int i = threadIdx.x; i < CHLEN * 2 * DSTATE; i += 256) {
    const int t = i >> 5, s = i & 31;
    BCsh[t][s] = xdbl[(size_t)(chunk * CHLEN + t) * 64 + 32 + s];
  }
  __syncthreads();
  float Avl2[DSTATE];
#pragma unroll
  for (int s = 0; s < DSTATE; ++s)
    Avl2[s] = -expf(A_log[d * DSTATE + s]) * LOG2E;
  float st[DSTATE];
  const size_t base = (size_t)chunk * DINNER * DSTATE + (size_t)d * DSTATE;
#pragma unroll
  for (int s = 0; s < DSTATE; ++s) st[s] = s0[base + s];
  const float Dv = Dsk[d];
  const size_t col = (size_t)chunk * CHLEN * DINNER + d;
  const size_t zcol = (size_t)chunk * CHLEN * 2 * DINNER + DINNER + d;
  for (int t0 = 0; t0 < CHLEN; t0 += 4) {
    float dl[4], xv[4], zv[4];
#pragma unroll
    for (int u = 0; u < 4; ++u) {
      const size_t idx = col + (size_t)(t0 + u) * DINNER;
      dl[u] = delta[idx];
      xv[u] = xc[idx];
      zv[u] = xz[zcol + (size_t)(t0 + u) * 2 * DINNER];
    }
    ushort yo[4];
#pragma unroll
    for (int u = 0; u < 4; ++u) {
      const float du = dl[u] * xv[u];
      float yv = 0.f;
#pragma unroll
      for (int s = 0; s < DSTATE; ++s) {
        const float a = exp2f(dl[u] * Avl2[s]);
        st[s] = fmaf(a, st[s], du * BCsh[t0 + u][s]);
        yv = fmaf(st[s], BCsh[t0 + u][DSTATE + s], yv);
      }
      yo[u] = f2bf((yv + xv[u] * Dv) * siluf(zv[u]));
    }
#pragma unroll
    for (int u = 0; u < 4; ++u)
      y[col + (size_t)(t0 + u) * DINNER] = yo[u];
  }
}

// ---------------- attention scores: tanh(h@Wa1+ba1)@Wa2+ba2 ---------------
__global__ __launch_bounds__(256) void attn_scores_k(
    const float* __restrict__ h, const float* __restrict__ Wa1,
    const float* __restrict__ ba1, const float* __restrict__ Wa2,
    const float* __restrict__ ba2, float* __restrict__ scores) {
  __shared__ float hs[8][DMODEL];
  __shared__ float part[8][2][ATTH];
  __shared__ float red[8][2];
  const int tid = threadIdx.x;
  const int j = tid & 127;
  const int half = tid >> 7;
  const int t0 = blockIdx.x * 8;
  for (int i = tid; i < 8 * DMODEL / 4; i += 256) {
    const int rr = i >> 7, cc = i & 127;
    *(float4*)&hs[rr][cc * 4] = *(const float4*)&h[(size_t)(t0 + rr) * DMODEL + cc * 4];
  }
  __syncthreads();
  float acc[8];
#pragma unroll
  for (int rr = 0; rr < 8; ++rr) acc[rr] = 0.f;
  const int kbase = half * 256;
  for (int k0 = 0; k0 < 256; k0 += 4) {
    float wv[4];
#pragma unroll
    for (int u = 0; u < 4; ++u)
      wv[u] = Wa1[(size_t)(kbase + k0 + u) * ATTH + j];
#pragma unroll
    for (int rr = 0; rr < 8; ++rr) {
      const float4 hv = *(const float4*)&hs[rr][kbase + k0];
      acc[rr] = fmaf(hv.x, wv[0], acc[rr]);
      acc[rr] = fmaf(hv.y, wv[1], acc[rr]);
      acc[rr] = fmaf(hv.z, wv[2], acc[rr]);
      acc[rr] = fmaf(hv.w, wv[3], acc[rr]);
    }
  }
#pragma unroll
  for (int rr = 0; rr < 8; ++rr) part[rr][half][j] = acc[rr];
  __syncthreads();
  if (half == 0) {
    const float w2 = Wa2[j];
    const float b1 = ba1[j];
    const int wv_ = j >> 6;
#pragma unroll
    for (int rr = 0; rr < 8; ++rr) {
      float v = tanhf(part[rr][0][j] + part[rr][1][j] + b1) * w2;
      v = wave_sum(v);
      if ((j & 63) == 0) red[rr][wv_] = v;
    }
  }
  __syncthreads();
  if (tid < 8) scores[t0 + tid] = red[tid][0] + red[tid][1] + ba2[0];
}

__global__ __launch_bounds__(1024) void softmax_k(
    const float* __restrict__ s, float* __restrict__ aw) {
  const int tid = threadIdx.x;
  const int wave = tid >> 6, lane = tid & 63;
  const float4 v = *(const float4*)&s[tid * 4];
  float m = fmaxf(fmaxf(v.x, v.y), fmaxf(v.z, v.w));
  m = wave_max(m);
  __shared__ float redm[16];
  if (lane == 0) redm[wave] = m;
  __syncthreads();
  float bm = redm[0];
#pragma unroll
  for (int i = 1; i < 16; ++i) bm = fmaxf(bm, redm[i]);
  const float e0 = expf(v.x - bm), e1 = expf(v.y - bm);
  const float e2 = expf(v.z - bm), e3 = expf(v.w - bm);
  float sum = wave_sum((e0 + e1) + (e2 + e3));
  __shared__ float reds[16];
  if (lane == 0) reds[wave] = sum;
  __syncthreads();
  float Z = 0.f;
#pragma unroll
  for (int i = 0; i < 16; ++i) Z += reds[i];
  const float inv = 1.f / Z;
  float4 o;
  o.x = e0 * inv; o.y = e1 * inv; o.z = e2 * inv; o.w = e3 * inv;
  *(float4*)&aw[tid * 4] = o;
}

__global__ __launch_bounds__(256) void pool_partial_k(
    const float* __restrict__ aw, const float* __restrict__ h, float* __restrict__ part) {
  const int b = blockIdx.x;
  const int tid = threadIdx.x;
  float2 acc = make_float2(0.f, 0.f);
  for (int t = b * 64; t < b * 64 + 64; ++t) {
    const float w = aw[t];
    const float2 hv = *(const float2*)&h[(size_t)t * DMODEL + tid * 2];
    acc.x = fmaf(w, hv.x, acc.x);
    acc.y = fmaf(w, hv.y, acc.y);
  }
  *(float2*)&part[b * DMODEL + tid * 2] = acc;
}

__global__ __launch_bounds__(512) void pool_final_k(
    const float* __restrict__ part, const float* __restrict__ Wh,
    const float* __restrict__ bh, float* __restrict__ out) {
  const int d = threadIdx.x;
  float s = 0.f;
  for (int b = 0; b < 64; ++b) s += part[b * DMODEL + d];
  float v0 = wave_sum(s * Wh[d * 2 + 0]);
  float v1 = wave_sum(s * Wh[d * 2 + 1]);
  __shared__ float r0[8], r1[8];
  const int wave = d >> 6, lane = d & 63;
  if (lane == 0) { r0[wave] = v0; r1[wave] = v1; }
  __syncthreads();
  if (d == 0) {
    float o0 = bh[0], o1 = bh[1];
#pragma unroll
    for (int i = 0; i < 8; ++i) { o0 += r0[i]; o1 += r1[i]; }
    out[0] = o0;
    out[1] = o1;
  }
}

extern "C" void kernel_launch(void* const* d_in, const int* in_sizes, int n_in,
                              void* d_out, int out_size, void* d_ws, size_t ws_size,
                              hipStream_t stream) {
  const float* in_h = (const float*)d_in[0];
  const float* W_proj = (const float*)d_in[1];
  const float* b_proj = (const float*)d_in[2];
  const float* ln_w = (const float*)d_in[3];
  const float* ln_b = (const float*)d_in[4];
  const float* W_in = (const float*)d_in[5];
  const float* W_conv = (const float*)d_in[6];
  const float* b_conv = (const float*)d_in[7];
  const float* W_x = (const float*)d_in[8];
  const float* W_dt = (const float*)d_in[9];
  const float* b_dt = (const float*)d_in[10];
  const float* A_log = (const float*)d_in[11];
  const float* Dsk = (const float*)d_in[12];
  const float* W_out = (const float*)d_in[13];
  const float* norm_w = (const float*)d_in[14];
  const float* norm_b = (const float*)d_in[15];
  const float* Wa1 = (const float*)d_in[16];
  const float* ba1 = (const float*)d_in[17];
  const float* Wa2 = (const float*)d_in[18];
  const float* ba2 = (const float*)d_in[19];
  const float* Wh = (const float*)d_in[20];
  const float* bh = (const float*)d_in[21];
  float* out = (float*)d_out;

  float* ws = (float*)d_ws;
  size_t off = 0;
  auto alloc = [&](size_t n) {
    float* p = ws + off;
    off += (n + 63) & ~(size_t)63;
    return p;
  };
  float* res = alloc((size_t)LSEQ * DMODEL);
  float* hbuf = alloc((size_t)LSEQ * DMODEL);
  float* xz = alloc((size_t)LSEQ * 2 * DINNER);
  float* xc = alloc((size_t)LSEQ * DINNER);
  float* xdbl = alloc((size_t)LSEQ * 64);
  float* delta = alloc((size_t)LSEQ * DINNER);
  float* chA = alloc((size_t)DINNER * DSTATE * NCHUNK);
  float* chB = alloc((size_t)DINNER * DSTATE * NCHUNK);
  ushort* lnb_bf = (ushort*)alloc((size_t)LSEQ * DMODEL / 2);
  ushort* y_bf = (ushort*)alloc((size_t)LSEQ * DINNER / 2);
  ushort* in_bf = (ushort*)alloc((size_t)LSEQ * 1024 / 2);
  ushort* WprojT = (ushort*)alloc((size_t)DMODEL * 1024 / 2);
  ushort* W_inT = (ushort*)alloc((size_t)2 * 2048 * 512 / 2);
  ushort* W_outT = (ushort*)alloc((size_t)2 * 512 * 1024 / 2);
  (void)ws_size;
  float* s0b = chB;  // phaseB writes prefix-state in-place over chB
  float* hfin = xz;
  float* scores = xz + (size_t)LSEQ * DMODEL;
  float* aw = scores + LSEQ;
  float* part = aw + LSEQ;

  // 0. one-shot prep: input cast + all 5 weight transposes
  prep_k<<<5632, 256, 0, stream>>>(in_h, in_bf, W_proj, WprojT, W_in, W_inT,
                                   W_out, W_outT);
  // 1. proj GEMM (relu+bias) -> res
  gemm_bf16<64, 128, ACT_RELU, true>
      <<<dim3(DMODEL / 128, LSEQ / 64), 256, 0, stream>>>(
          in_bf, WprojT, b_proj, res, LSEQ, DMODEL, 1024);

  const float* cur = res;
  for (int l = 0; l < 2; ++l) {
    layernorm_k<true><<<LSEQ / 4, 256, 0, stream>>>(
        cur, nullptr, ln_w + l * DMODEL, ln_b + l * DMODEL, lnb_bf);
    gemm_bf16<128, 128, ACT_NONE, false>
        <<<dim3(2 * DINNER / 128, LSEQ / 128), 256, 0, stream>>>(
            lnb_bf, W_inT + (size_t)l * 2048 * 512, nullptr, xz, LSEQ,
            2 * DINNER, DMODEL);
    conv_silu_k<<<LSEQ * DINNER / 256, 256, 0, stream>>>(
        xz, W_conv + l * DINNER * 4, b_conv + l * DINNER, xc);
    gemm_skinny64<<<LSEQ / 8, 256, 0, stream>>>(
        xc, W_x + (size_t)l * DINNER * 64, xdbl);
    gemm_f32<128, 128, 16, 8, 8, ACT_SOFTPLUS, true>
        <<<dim3(DINNER / 128, LSEQ / 128), 256, 0, stream>>>(
            xdbl, 64, W_dt + (size_t)l * DTRANK * DINNER, b_dt + l * DINNER,
            delta, LSEQ, DINNER, DTRANK);
    const float* Al = A_log + (size_t)l * DINNER * DSTATE;
    scan_phaseA<<<NCHUNK * 4, 256, 0, stream>>>(delta, xc, xdbl, Al, chA, chB);
    scan_phaseB<<<DINNER * DSTATE / 64, 64, 0, stream>>>(chA, chB, s0b);
    scan_phaseC<<<NCHUNK * 4, 256, 0, stream>>>(
        delta, xc, xdbl, Al, Dsk + l * DINNER, s0b, xz, y_bf);
    gemm_bf16<64, 128, ACT_NONE, false>
        <<<dim3(DMODEL / 128, LSEQ / 64), 256, 0, stream>>>(
            y_bf, W_outT + (size_t)l * 512 * 1024, nullptr, hbuf, LSEQ, DMODEL,
            DINNER);
    cur = hbuf;
  }

  layernorm_k<false><<<LSEQ / 4, 256, 0, stream>>>(cur, res, norm_w, norm_b, hfin);
  attn_scores_k<<<LSEQ / 8, 256, 0, stream>>>(hfin, Wa1, ba1, Wa2, ba2, scores);
  softmax_k<<<1, 1024, 0, stream>>>(scores, aw);
  pool_partial_k<<<64, 256, 0, stream>>>(aw, hfin, part);
  pool_final_k<<<1, 512, 0, stream>>>(part, Wh, bh, out);
}